// Round 3
// baseline (376.939 us; speedup 1.0000x reference)
//
#include <hip/hip_runtime.h>
#include <cstdint>
#include <cstddef>

typedef __bf16 bf16x8 __attribute__((ext_vector_type(8)));
typedef float f32x4 __attribute__((ext_vector_type(4)));
typedef unsigned short u16x8 __attribute__((ext_vector_type(8)));
typedef unsigned short u16x4 __attribute__((ext_vector_type(4)));
typedef short s16x4 __attribute__((ext_vector_type(4)));
typedef unsigned short u16;

#define L_SEQ 2048
#define D_HALF 1024
#define HDIM 64
// exp(s/sqrt(128)) = exp2(s * EXP2_SCALE); folded into the Q-projection
// epilogue (f32 multiply before the bf16 round -> precision-neutral).
static constexpr float EXP2_SCALE = 0.12751742552639395f; // (1/sqrt(128))*log2(e)

__device__ inline u16 f2b(float f) {
  uint32_t u; __builtin_memcpy(&u, &f, 4);
  u = u + 0x7FFFu + ((u >> 16) & 1u);   // RNE
  return (u16)(u >> 16);
}

// single-instruction f32x2 -> packed bf16 (RNE); no builtin on gfx950.
__device__ inline uint32_t cvt_pk_bf16(float lo, float hi) {
  uint32_t r;
  asm("v_cvt_pk_bf16_f32 %0, %1, %2" : "=v"(r) : "v"(lo), "v"(hi));
  return r;
}

// async global->LDS, 16B per lane; LDS dest is wave-uniform base + lane*16.
#define GLOAD16(gp, lp) __builtin_amdgcn_global_load_lds( \
    (const __attribute__((address_space(1))) unsigned int*)(gp), \
    (__attribute__((address_space(3))) unsigned int*)(lp), 16, 0, 0)

// ---------------------------------------------------------------------------
// f32 -> bf16 converters.
// ---------------------------------------------------------------------------
__global__ __launch_bounds__(256)
void convx(const float* xa, const float* xb, u16* dst) {
  const float* s = blockIdx.y ? xb : xa;
  size_t i = ((size_t)blockIdx.x * 256 + threadIdx.x) * 8;
  float4 v0 = *(const float4*)(s + i);
  float4 v1 = *(const float4*)(s + i + 4);
  u16x8 p;
  p[0] = f2b(v0.x); p[1] = f2b(v0.y); p[2] = f2b(v0.z); p[3] = f2b(v0.w);
  p[4] = f2b(v1.x); p[5] = f2b(v1.y); p[6] = f2b(v1.z); p[7] = f2b(v1.w);
  *(u16x8*)&dst[(size_t)blockIdx.y * 4194304 + i] = p;
}

struct CArg8 { const float* src[8]; };
__global__ __launch_bounds__(256)
void convw8(CArg8 a, u16* dst) {
  const int z = blockIdx.y;
  const float* s = a.src[z];
  size_t i = ((size_t)blockIdx.x * 256 + threadIdx.x) * 8;
  float4 v0 = *(const float4*)(s + i);
  float4 v1 = *(const float4*)(s + i + 4);
  u16x8 p;
  p[0] = f2b(v0.x); p[1] = f2b(v0.y); p[2] = f2b(v0.z); p[3] = f2b(v0.w);
  p[4] = f2b(v1.x); p[5] = f2b(v1.y); p[6] = f2b(v1.z); p[7] = f2b(v1.w);
  *(u16x8*)&dst[(size_t)z * 1048576 + i] = p;
}

// ---------------------------------------------------------------------------
// Batched GEMM: C[m][n] = sum_k A[m][k] * W[n][k]  (torch-Linear x@W.T form).
// m97-faithful structure this round: SINGLE 32KB LDS buffer, global_load_lds
// width=16 staged between two barriers per K-step, no launch_bounds waves cap
// (VGPR floats -> ~3 blocks/CU; cross-block wave overlap hides the vmcnt
// drain, m114). Source-XOR-swizzle + matching read-XOR kept from round 2
// (correctness-verified; free). alpha: folded scalar on the bf16 epilogue.
// RESID: + f32 residual -> f32 z. vt: transposed epilogue to vT[b][h*64+d][t].
// ---------------------------------------------------------------------------
struct GArg { const u16* A; const u16* W; u16* C; const float* R; float* Z;
              int vt; float alpha; };
struct GArgs { GArg g[6]; };

template <bool RESID>
__global__ __launch_bounds__(256)
void gemm_nt(GArgs args, int M, int N, int K) {
  GArg ga = args.g[blockIdx.z];
  __shared__ __attribute__((aligned(16))) u16 As[8192];   // [128][64] linear
  __shared__ __attribute__((aligned(16))) u16 Bs[8192];

  const int tid = threadIdx.x;
  const int wv = tid >> 6, lane = tid & 63;
  const int lane15 = lane & 15, quad = lane >> 4;
  const int m0 = blockIdx.y * 128, n0 = blockIdx.x * 128;
  const int wm = (wv >> 1) * 64, wn = (wv & 1) * 64;

  // staging: wave issue j covers LDS rows wv*32+j*8 .. +7 (1KB linear).
  // lane -> row wv*32+j*8+(lane>>3), physical chunk lane&7. Source chunk is
  // XOR-swizzled so that the read-side XOR recovers logical order.
  const int srow = lane >> 3;
  const int scol = ((lane & 7) ^ srow) * 8;      // swizzled source u16 col

  const u16* pA[4]; const u16* pW[4]; int lo[4];
#pragma unroll
  for (int j = 0; j < 4; j++) {
    int r = wv * 32 + j * 8;
    pA[j] = ga.A + (size_t)(m0 + r + srow) * K + scol;
    pW[j] = ga.W + (size_t)(n0 + r + srow) * K + scol;
    lo[j] = r * 64;
  }

  f32x4 acc[4][4] = {};
  const int swz = (lane15 & 7) << 4;             // read-side XOR (bytes)

  for (int k0 = 0; k0 < K; k0 += 64) {
    __syncthreads();     // WAR: previous tile's ds_reads drained
#pragma unroll
    for (int j = 0; j < 4; j++) {
      GLOAD16(pA[j] + k0, &As[lo[j]]);
      GLOAD16(pW[j] + k0, &Bs[lo[j]]);
    }
    __syncthreads();     // vmcnt(0) drain -> tile resident
    const char* ab = (const char*)As;
    const char* bb = (const char*)Bs;
#pragma unroll
    for (int kk = 0; kk < 2; kk++) {
      const int cb = kk * 64 + quad * 16;
      bf16x8 af[4], bw[4];
#pragma unroll
      for (int i = 0; i < 4; i++)
        af[i] = *(const bf16x8*)(ab + (wm + i * 16 + lane15) * 128 + (cb ^ swz));
#pragma unroll
      for (int j = 0; j < 4; j++)
        bw[j] = *(const bf16x8*)(bb + (wn + j * 16 + lane15) * 128 + (cb ^ swz));
#pragma unroll
      for (int i = 0; i < 4; i++)
#pragma unroll
        for (int j = 0; j < 4; j++)
          acc[i][j] = __builtin_amdgcn_mfma_f32_16x16x32_bf16(af[i], bw[j], acc[i][j], 0, 0, 0);
    }
  }

  const float al = ga.alpha;
  if (!RESID && ga.vt) {
    // transposed epilogue: vT[b][gn][t], 4 consecutive tokens per u16x4
#pragma unroll
    for (int i = 0; i < 4; i++)
#pragma unroll
      for (int j = 0; j < 4; j++) {
        int gm0 = m0 + wm + i * 16 + quad * 4;       // token base (mult of 4)
        int gn  = n0 + wn + j * 16 + lane15;         // feature = h*64+d
        int bb2 = gm0 >> 11, t = gm0 & 2047;
        u16x4 pk;
#pragma unroll
        for (int r = 0; r < 4; r++) pk[r] = f2b(acc[i][j][r] * al);
        *(u16x4*)&ga.C[(size_t)bb2 * 2097152 + (size_t)gn * 2048 + t] = pk;
      }
  } else {
#pragma unroll
    for (int i = 0; i < 4; i++)
#pragma unroll
      for (int j = 0; j < 4; j++)
#pragma unroll
        for (int r = 0; r < 4; r++) {
          int gm = m0 + wm + i * 16 + quad * 4 + r;  // C/D: row=quad*4+reg
          int gn = n0 + wn + j * 16 + lane15;        //      col=lane&15
          size_t idx = (size_t)gm * N + gn;
          if (RESID) ga.Z[idx] = acc[i][j][r] + ga.R[idx];
          else       ga.C[idx] = f2b(acc[i][j][r] * al);
        }
  }
}

// ---------------------------------------------------------------------------
// Cross flash-attention, no-max softmax. This round: 2-DEEP SOFTWARE
// PIPELINE to break the serial QK->exp->PV chain (counters: MfmaUtil 44 +
// VALUBusy 43, both pipes alternating, 57% stall).
// Interval between barriers (it): [W: stage tile it+1 -> buf nxt] barrier
// [QK(it+1) MFMAs from Ks[nxt] issue FIRST; exp(it) VALU runs while they
// are in flight; PV(it) from registers (pa + vf); vf(it+1) <- Vt[nxt];
// glb loads tile it+2]. V is consumed from REGISTERS (vf, loaded one
// interval ahead) -- required for 1-barrier safety: reads of a buffer only
// occur in the interval where it is 'nxt', writes always target 'nxt'.
// Layouts unchanged: swapped QK^T (P lane-local), PV via 16x16x16bf16_1k,
// XOR-swizzled [64][64] LDS, scale pre-folded into Q.
// ---------------------------------------------------------------------------
#define SWZ(row, bcol) ((row) * 128 + ((bcol) ^ (((row) & 7) << 4)))

__global__ __launch_bounds__(256)
void attn_kernel(const u16* q_a, const u16* k_a, const u16* vt_a,
                 const u16* q_b, const u16* k_b, const u16* vt_b,
                 u16* o_a, u16* o_b) {
  const int br = blockIdx.z;
  const u16* Q  = br ? q_b : q_a;
  const u16* Kp = br ? k_a : k_b;
  const u16* Vp = br ? vt_a : vt_b;
  u16* O = br ? o_b : o_a;
  const int bh = blockIdx.y;
  const int b = bh >> 4, h = bh & 15;
  const int q0 = blockIdx.x * 128;

  const int tid = threadIdx.x, wv = tid >> 6, lane = tid & 63;
  const int lane15 = lane & 15, quad = lane >> 4;

  __shared__ __attribute__((aligned(16))) u16 Ks[2][4096];   // [64][64] swz
  __shared__ __attribute__((aligned(16))) u16 Vt[2][4096];   // [d][key] swz

  const size_t base   = ((size_t)b * L_SEQ) * D_HALF + (size_t)h * HDIM;
  const size_t vbase  = (size_t)b * 2097152 + (size_t)(h * 64) * 2048;

  // staging slots: thread covers 2 u16x8 chunks of each 64x64 tile
  const int c1 = tid + 256;
  const int r0 = tid >> 3, cb0 = (tid & 7) * 16;   // byte col
  const int r1 = c1 >> 3,  cb1 = (c1 & 7) * 16;
  const int wo0 = SWZ(r0, cb0), wo1 = SWZ(r1, cb1);

  // two q fragments per wave: rows q0 + wv*32 + f*16 + lane15
  bf16x8 qf[2][2];
#pragma unroll
  for (int f = 0; f < 2; f++) {
    const int qrow = q0 + wv * 32 + f * 16 + lane15;
#pragma unroll
    for (int c = 0; c < 2; c++)
      qf[f][c] = *(const bf16x8*)&Q[base + (size_t)qrow * D_HALF + c * 32 + quad * 8];
  }

  // stage tile 0
  u16x8 kr0 = *(const u16x8*)&Kp[base + (size_t)r0 * D_HALF + cb0 / 2];
  u16x8 kr1 = *(const u16x8*)&Kp[base + (size_t)r1 * D_HALF + cb1 / 2];
  u16x8 vr0 = *(const u16x8*)&Vp[vbase + (size_t)r0 * 2048 + cb0 / 2];
  u16x8 vr1 = *(const u16x8*)&Vp[vbase + (size_t)r1 * 2048 + cb1 / 2];
  *(u16x8*)((char*)Ks[0] + wo0) = kr0;
  *(u16x8*)((char*)Ks[0] + wo1) = kr1;
  *(u16x8*)((char*)Vt[0] + wo0) = vr0;
  *(u16x8*)((char*)Vt[0] + wo1) = vr1;
  __syncthreads();

  // prefetch tile 1 into staging regs
  kr0 = *(const u16x8*)&Kp[base + (size_t)(64 + r0) * D_HALF + cb0 / 2];
  kr1 = *(const u16x8*)&Kp[base + (size_t)(64 + r1) * D_HALF + cb1 / 2];
  vr0 = *(const u16x8*)&Vp[vbase + (size_t)r0 * 2048 + 64 + cb0 / 2];
  vr1 = *(const u16x8*)&Vp[vbase + (size_t)r1 * 2048 + 64 + cb1 / 2];

  // QK(0) -> s_cur; vf(0) <- Vt[0]
  f32x4 s_cur[2][4];
  {
    const char* kb = (const char*)Ks[0];
#pragma unroll
    for (int nt = 0; nt < 4; nt++) {
      const int krow = nt * 16 + lane15;
      bf16x8 kb0 = *(const bf16x8*)(kb + SWZ(krow, quad * 16));
      bf16x8 kb1 = *(const bf16x8*)(kb + SWZ(krow, 64 + quad * 16));
#pragma unroll
      for (int f = 0; f < 2; f++) {
        f32x4 a0 = {};
        a0 = __builtin_amdgcn_mfma_f32_16x16x32_bf16(kb0, qf[f][0], a0, 0, 0, 0);
        a0 = __builtin_amdgcn_mfma_f32_16x16x32_bf16(kb1, qf[f][1], a0, 0, 0, 0);
        s_cur[f][nt] = a0;
      }
    }
  }
  s16x4 vf[4][4];
  {
    const char* vb = (const char*)Vt[0];
#pragma unroll
    for (int dt = 0; dt < 4; dt++)
#pragma unroll
      for (int nt = 0; nt < 4; nt++)
        vf[dt][nt] = *(const s16x4*)(vb + SWZ(dt * 16 + lane15, nt * 32 + quad * 8));
  }

  f32x4 oacc[2][4] = {};
  float lsum[2] = {0.f, 0.f};

#pragma unroll 2
  for (int it = 0; it < 32; it++) {
    const int nxtb = (it + 1) & 1;
    char* kn = (char*)Ks[nxtb];
    char* vn = (char*)Vt[nxtb];
    if (it < 31) {                     // stage tile it+1 -> buf nxt
      *(u16x8*)(kn + wo0) = kr0;
      *(u16x8*)(kn + wo1) = kr1;
      *(u16x8*)(vn + wo0) = vr0;
      *(u16x8*)(vn + wo1) = vr1;
    }
    __syncthreads();

    // QK(it+1) FIRST: 16 MFMAs go in flight, exp(it) overlaps them.
    f32x4 s_nx[2][4];
    if (it < 31) {
      __builtin_amdgcn_s_setprio(1);
#pragma unroll
      for (int nt = 0; nt < 4; nt++) {
        const int krow = nt * 16 + lane15;
        bf16x8 kb0 = *(const bf16x8*)(kn + SWZ(krow, quad * 16));
        bf16x8 kb1 = *(const bf16x8*)(kn + SWZ(krow, 64 + quad * 16));
#pragma unroll
        for (int f = 0; f < 2; f++) {
          f32x4 a0 = {};
          a0 = __builtin_amdgcn_mfma_f32_16x16x32_bf16(kb0, qf[f][0], a0, 0, 0, 0);
          a0 = __builtin_amdgcn_mfma_f32_16x16x32_bf16(kb1, qf[f][1], a0, 0, 0, 0);
          s_nx[f][nt] = a0;
        }
      }
      __builtin_amdgcn_s_setprio(0);
      if (it < 30) {                   // glb loads tile it+2
        const int kt = (it + 2) * 64;
        kr0 = *(const u16x8*)&Kp[base + (size_t)(kt + r0) * D_HALF + cb0 / 2];
        kr1 = *(const u16x8*)&Kp[base + (size_t)(kt + r1) * D_HALF + cb1 / 2];
        vr0 = *(const u16x8*)&Vp[vbase + (size_t)r0 * 2048 + kt + cb0 / 2];
        vr1 = *(const u16x8*)&Vp[vbase + (size_t)r1 * 2048 + kt + cb1 / 2];
      }
    }

    // exp(it): p = exp2(s)  (scale pre-folded into Q); keys lane-local ->
    // lane-local partial row sum; pa[f][nt] IS the 16x16x16 A-fragment.
    s16x4 pa[2][4];
#pragma unroll
    for (int f = 0; f < 2; f++)
#pragma unroll
      for (int nt = 0; nt < 4; nt++) {
        float p0 = __builtin_amdgcn_exp2f(s_cur[f][nt][0]);
        float p1 = __builtin_amdgcn_exp2f(s_cur[f][nt][1]);
        float p2 = __builtin_amdgcn_exp2f(s_cur[f][nt][2]);
        float p3 = __builtin_amdgcn_exp2f(s_cur[f][nt][3]);
        lsum[f] += (p0 + p1) + (p2 + p3);
        union { uint32_t u[2]; s16x4 v; } cv;
        cv.u[0] = cvt_pk_bf16(p0, p1);
        cv.u[1] = cvt_pk_bf16(p2, p3);
        pa[f][nt] = cv.v;
      }

    // PV(it): registers only (pa + vf).
    __builtin_amdgcn_s_setprio(1);
#pragma unroll
    for (int dt = 0; dt < 4; dt++)
#pragma unroll
      for (int f = 0; f < 2; f++) {
        f32x4 t = oacc[f][dt];
#pragma unroll
        for (int nt = 0; nt < 4; nt++)
          t = __builtin_amdgcn_mfma_f32_16x16x16bf16_1k(pa[f][nt], vf[dt][nt], t, 0, 0, 0);
        oacc[f][dt] = t;
      }
    __builtin_amdgcn_s_setprio(0);

    if (it < 31) {
      // vf(it+1) <- Vt[nxt]; s_cur <- s_nx (renamed away by unroll 2)
#pragma unroll
      for (int dt = 0; dt < 4; dt++)
#pragma unroll
        for (int nt = 0; nt < 4; nt++)
          vf[dt][nt] = *(const s16x4*)(vn + SWZ(dt * 16 + lane15, nt * 32 + quad * 8));
#pragma unroll
      for (int f = 0; f < 2; f++)
#pragma unroll
        for (int nt = 0; nt < 4; nt++)
          s_cur[f][nt] = s_nx[f][nt];
    }
  }

  // finalize: lsum[f] holds this lane's partial for q = lane15; sum the 4
  // quads (xor16+xor32), then redistribute 1/l to C-layout rows (quad*4+r).
#pragma unroll
  for (int f = 0; f < 2; f++) {
    float lt = lsum[f];
    lt += __shfl_xor(lt, 16);
    lt += __shfl_xor(lt, 32);
    lsum[f] = lt;                    // every lane: total for q = lane15
  }
#pragma unroll
  for (int f = 0; f < 2; f++) {
    float linv[4];
#pragma unroll
    for (int r = 0; r < 4; r++)
      linv[r] = 1.0f / __shfl(lsum[f], quad * 4 + r);
#pragma unroll
    for (int dt = 0; dt < 4; dt++)
#pragma unroll
      for (int r = 0; r < 4; r++) {
        float val = oacc[f][dt][r] * linv[r];
        O[base + (size_t)(q0 + wv * 32 + f * 16 + quad * 4 + r) * D_HALF
          + dt * 16 + lane15] = f2b(val);
      }
  }
}

// ---------------------------------------------------------------------------
// LayerNorm over f32 z rows -> f32 out. One block per row.
// ---------------------------------------------------------------------------
__global__ __launch_bounds__(256)
void ln_kernel(const float* zA, const float* zB,
               const float* gA, const float* bA, const float* gB, const float* bB,
               float* out) {
  const int row = blockIdx.x, br = blockIdx.y;
  const float* z = (br ? zB : zA) + (size_t)row * D_HALF;
  const float* g  = br ? gB : gA;
  const float* be = br ? bB : bA;
  float* o = out + (size_t)br * ((size_t)4096 * D_HALF) + (size_t)row * D_HALF;

  float4 v = ((const float4*)z)[threadIdx.x];
  float s  = v.x + v.y + v.z + v.w;
  float s2 = v.x * v.x + v.y * v.y + v.z * v.z + v.w * v.w;
#pragma unroll
  for (int off = 32; off > 0; off >>= 1) {
    s  += __shfl_down(s, off);
    s2 += __shfl_down(s2, off);
  }
  __shared__ float red[8];
  int w = threadIdx.x >> 6, ln = threadIdx.x & 63;
  if (ln == 0) { red[w] = s; red[4 + w] = s2; }
  __syncthreads();
  if (threadIdx.x == 0) {
    red[0] = red[0] + red[1] + red[2] + red[3];
    red[4] = red[4] + red[5] + red[6] + red[7];
  }
  __syncthreads();
  float mu  = red[0] * (1.0f / 1024.0f);
  float var = red[4] * (1.0f / 1024.0f) - mu * mu;
  float rs  = rsqrtf(fmaxf(var, 0.0f) + 1e-5f);

  int col = threadIdx.x * 4;
  float4 gv = ((const float4*)g)[threadIdx.x];
  float4 bv = ((const float4*)be)[threadIdx.x];
  float4 ov;
  ov.x = (v.x - mu) * rs * gv.x + bv.x;
  ov.y = (v.y - mu) * rs * gv.y + bv.y;
  ov.z = (v.z - mu) * rs * gv.z + bv.z;
  ov.w = (v.w - mu) * rs * gv.w + bv.w;
  *(float4*)&o[col] = ov;
}

// ---------------------------------------------------------------------------
extern "C" void kernel_launch(void* const* d_in, const int* in_sizes, int n_in,
                              void* d_out, int out_size, void* d_ws, size_t ws_size,
                              hipStream_t stream) {
  const float* x_a     = (const float*)d_in[0];
  const float* x_b     = (const float*)d_in[1];
  const float* Wq_a    = (const float*)d_in[2];
  const float* Wq_b    = (const float*)d_in[3];
  const float* Wk_a    = (const float*)d_in[4];
  const float* Wk_b    = (const float*)d_in[5];
  const float* Wv_a    = (const float*)d_in[6];
  const float* Wv_b    = (const float*)d_in[7];
  const float* Wo_a    = (const float*)d_in[8];
  const float* Wo_b    = (const float*)d_in[9];
  const float* gamma_a = (const float*)d_in[10];
  const float* beta_a  = (const float*)d_in[11];
  const float* gamma_b = (const float*)d_in[12];
  const float* beta_b  = (const float*)d_in[13];

  // Workspace map (ws = 64 MB = 32M u16; BUF = 4M u16 = 8 MB):
  //   slots 0-5: q_a,k_a,vt_a,q_b,k_b,vt_b (QKV outputs, read by attn)
  //   ws+24M u16 (48 MB): 8 bf16 weights (Wq/Wk/Wv a,b = 12 MB; Wo a,b = 4 MB)
  //   phase 3: z_a/z_b f32 overwrite slots 0-3 (dead after attn)
  // d_out (32 MB) doubles as scratch:
  //   phase 1: xbf_a/xbf_b (16 MB) read by QKV GEMM
  //   phase 2: o_a/o_b (16 MB) written by attn, read by out-proj
  //   ln writes the final f32 output last.
  const size_t BUF = (size_t)4096 * 1024;
  u16* ws   = (u16*)d_ws;
  u16* q_a  = ws + 0 * BUF; u16* k_a  = ws + 1 * BUF; u16* vt_a = ws + 2 * BUF;
  u16* q_b  = ws + 3 * BUF; u16* k_b  = ws + 4 * BUF; u16* vt_b = ws + 5 * BUF;
  u16* wall = ws + 6 * BUF;                    // 8 x 1M-u16 bf16 weights
  float* z_a = (float*)(ws + 0 * BUF);
  float* z_b = (float*)(ws + 2 * BUF);

  u16* xbf_a = (u16*)d_out;
  u16* xbf_b = xbf_a + 4194304;
  u16* o_a   = (u16*)d_out;                    // reuses xbf region (dead)
  u16* o_b   = o_a + 4194304;

  const int M = 4096, N = 1024, K = 1024;

  convx<<<dim3(2048, 2), 256, 0, stream>>>(x_a, x_b, xbf_a);

  CArg8 cw;
  cw.src[0] = Wq_a; cw.src[1] = Wk_a; cw.src[2] = Wv_a;
  cw.src[3] = Wq_b; cw.src[4] = Wk_b; cw.src[5] = Wv_b;
  cw.src[6] = Wo_a; cw.src[7] = Wo_b;
  convw8<<<dim3(512, 8), 256, 0, stream>>>(cw, wall);

  GArgs qkv;
  qkv.g[0] = GArg{xbf_a, wall + 0 * 1048576, q_a,  nullptr, nullptr, 0, EXP2_SCALE};
  qkv.g[1] = GArg{xbf_a, wall + 1 * 1048576, k_a,  nullptr, nullptr, 0, 1.0f};
  qkv.g[2] = GArg{xbf_a, wall + 2 * 1048576, vt_a, nullptr, nullptr, 1, 1.0f};
  qkv.g[3] = GArg{xbf_b, wall + 3 * 1048576, q_b,  nullptr, nullptr, 0, EXP2_SCALE};
  qkv.g[4] = GArg{xbf_b, wall + 4 * 1048576, k_b,  nullptr, nullptr, 0, 1.0f};
  qkv.g[5] = GArg{xbf_b, wall + 5 * 1048576, vt_b, nullptr, nullptr, 1, 1.0f};
  gemm_nt<false><<<dim3(8, 32, 6), 256, 0, stream>>>(qkv, M, N, K);

  attn_kernel<<<dim3(16, 32, 2), 256, 0, stream>>>(q_a, k_a, vt_a, q_b, k_b, vt_b, o_a, o_b);

  GArgs op;
  op.g[0] = GArg{o_a, wall + 6 * 1048576, nullptr, x_a, z_a, 0, 1.0f};
  op.g[1] = GArg{o_b, wall + 7 * 1048576, nullptr, x_b, z_b, 0, 1.0f};
  op.g[2] = op.g[0]; op.g[3] = op.g[0]; op.g[4] = op.g[0]; op.g[5] = op.g[0];
  gemm_nt<true><<<dim3(8, 32, 2), 256, 0, stream>>>(op, M, N, K);

  ln_kernel<<<dim3(4096, 2), 256, 0, stream>>>(z_a, z_b, gamma_a, beta_a,
                                               gamma_b, beta_b, (float*)d_out);
}

// Round 4
// 341.970 us; speedup vs baseline: 1.1023x; 1.1023x over previous
//
#include <hip/hip_runtime.h>
#include <cstdint>
#include <cstddef>

typedef __bf16 bf16x8 __attribute__((ext_vector_type(8)));
typedef float f32x4 __attribute__((ext_vector_type(4)));
typedef unsigned short u16x8 __attribute__((ext_vector_type(8)));
typedef unsigned short u16x4 __attribute__((ext_vector_type(4)));
typedef short s16x4 __attribute__((ext_vector_type(4)));
typedef unsigned short u16;

#define L_SEQ 2048
#define D_HALF 1024
#define HDIM 64
// exp(s/sqrt(128)) = exp2(s * EXP2_SCALE); folded into the Q-projection
// epilogue (f32 multiply before the bf16 round -> precision-neutral).
static constexpr float EXP2_SCALE = 0.12751742552639395f; // (1/sqrt(128))*log2(e)

__device__ inline u16 f2b(float f) {
  uint32_t u; __builtin_memcpy(&u, &f, 4);
  u = u + 0x7FFFu + ((u >> 16) & 1u);   // RNE
  return (u16)(u >> 16);
}

// single-instruction f32x2 -> packed bf16 (RNE); no builtin on gfx950.
__device__ inline uint32_t cvt_pk_bf16(float lo, float hi) {
  uint32_t r;
  asm("v_cvt_pk_bf16_f32 %0, %1, %2" : "=v"(r) : "v"(lo), "v"(hi));
  return r;
}

// async global->LDS, 16B per lane; LDS dest is wave-uniform base + lane*16.
#define GLOAD16(gp, lp) __builtin_amdgcn_global_load_lds( \
    (const __attribute__((address_space(1))) unsigned int*)(gp), \
    (__attribute__((address_space(3))) unsigned int*)(lp), 16, 0, 0)

// ---------------------------------------------------------------------------
// Fused f32 -> bf16 converter (x planes + 8 weight matrices, one dispatch).
// id < 4096: x planes (2048 blocks each); else weights (512 blocks each).
// ---------------------------------------------------------------------------
struct CArgAll { const float* src[10]; u16* dst[10]; };
__global__ __launch_bounds__(256)
void convall(CArgAll a) {
  const int id = blockIdx.x;
  const float* s; u16* d; int blk;
  if (id < 4096) { int p = id >> 11; blk = id & 2047; s = a.src[p]; d = a.dst[p]; }
  else { int w = (id - 4096) >> 9; blk = (id - 4096) & 511; s = a.src[2 + w]; d = a.dst[2 + w]; }
  size_t i = ((size_t)blk * 256 + threadIdx.x) * 8;
  float4 v0 = *(const float4*)(s + i);
  float4 v1 = *(const float4*)(s + i + 4);
  u16x8 p;
  p[0] = f2b(v0.x); p[1] = f2b(v0.y); p[2] = f2b(v0.z); p[3] = f2b(v0.w);
  p[4] = f2b(v1.x); p[5] = f2b(v1.y); p[6] = f2b(v1.z); p[7] = f2b(v1.w);
  *(u16x8*)&d[i] = p;
}

// ---------------------------------------------------------------------------
// Batched GEMM: C[m][n] = sum_k A[m][k] * W[n][k]  (torch-Linear x@W.T form).
// This round: counted-vmcnt 2-deep pipeline (T4). Double-buffered LDS, raw
// s_barrier (NOT __syncthreads -- that emits vmcnt(0) and drains the async
// queue). Per K-step: MFMA(cur) -> barrier (read-drain) -> stage tile t+2
// into cur's slot -> s_waitcnt vmcnt(8) (waits ONLY t+1's loads, which had
// the whole MFMA phase to land; t+2's 8 stay in flight) -> barrier
// (publish t+1). sched_barrier(0) fences stop hipcc hoisting ds_reads
// across the barriers (rule 18/21). Source-XOR swizzle on the gload src +
// matching read-XOR (rule 21 both-sides). alpha: folded scalar epilogue.
// RESID: + f32 residual -> f32 z. vt: transposed epilogue to vT[b][hd][t].
// ---------------------------------------------------------------------------
struct GArg { const u16* A; const u16* W; u16* C; const float* R; float* Z;
              int vt; float alpha; };
struct GArgs { GArg g[6]; };

template <bool RESID>
__global__ __launch_bounds__(256)
void gemm_nt(GArgs args, int M, int N, int K) {
  GArg ga = args.g[blockIdx.z];
  __shared__ __attribute__((aligned(16))) u16 As[2][8192];   // [128][64] linear
  __shared__ __attribute__((aligned(16))) u16 Bs[2][8192];

  const int tid = threadIdx.x;
  const int wv = tid >> 6, lane = tid & 63;
  const int lane15 = lane & 15, quad = lane >> 4;
  const int m0 = blockIdx.y * 128, n0 = blockIdx.x * 128;
  const int wm = (wv >> 1) * 64, wn = (wv & 1) * 64;

  // staging: wave issue j covers LDS rows wv*32+j*8 .. +7 (1KB linear).
  // lane -> row wv*32+j*8+(lane>>3), physical chunk lane&7; source chunk
  // XOR-swizzled so the read-side XOR recovers logical order.
  const int srow = lane >> 3;
  const int scol = ((lane & 7) ^ srow) * 8;      // swizzled source u16 col

  const u16* pA[4]; const u16* pW[4]; int lo[4];
#pragma unroll
  for (int j = 0; j < 4; j++) {
    int r = wv * 32 + j * 8;
    pA[j] = ga.A + (size_t)(m0 + r + srow) * K + scol;
    pW[j] = ga.W + (size_t)(n0 + r + srow) * K + scol;
    lo[j] = r * 64;
  }

  f32x4 acc[4][4] = {};
  const int swz = (lane15 & 7) << 4;             // read-side XOR (bytes)
  const int NT = K >> 6;                         // 16 K-steps

  // prologue: stage tiles 0 and 1
#pragma unroll
  for (int j = 0; j < 4; j++) {
    GLOAD16(pA[j], &As[0][lo[j]]);
    GLOAD16(pW[j], &Bs[0][lo[j]]);
  }
#pragma unroll
  for (int j = 0; j < 4; j++) {
    GLOAD16(pA[j] + 64, &As[1][lo[j]]);
    GLOAD16(pW[j] + 64, &Bs[1][lo[j]]);
  }
  asm volatile("s_waitcnt vmcnt(8)" ::: "memory");   // tile 0 resident
  __builtin_amdgcn_s_barrier();
  __builtin_amdgcn_sched_barrier(0);

  for (int t = 0; t < NT; ++t) {
    const int cur = t & 1;
    const char* ab = (const char*)As[cur];
    const char* bb = (const char*)Bs[cur];
#pragma unroll
    for (int kk = 0; kk < 2; kk++) {
      const int cb = kk * 64 + quad * 16;
      bf16x8 af[4], bw[4];
#pragma unroll
      for (int i = 0; i < 4; i++)
        af[i] = *(const bf16x8*)(ab + (wm + i * 16 + lane15) * 128 + (cb ^ swz));
#pragma unroll
      for (int j = 0; j < 4; j++)
        bw[j] = *(const bf16x8*)(bb + (wn + j * 16 + lane15) * 128 + (cb ^ swz));
#pragma unroll
      for (int i = 0; i < 4; i++)
#pragma unroll
        for (int j = 0; j < 4; j++)
          acc[i][j] = __builtin_amdgcn_mfma_f32_16x16x32_bf16(af[i], bw[j], acc[i][j], 0, 0, 0);
    }
    // all ds_reads above were consumed by MFMAs -> complete at barrier.
    __builtin_amdgcn_sched_barrier(0);
    __builtin_amdgcn_s_barrier();                 // read-drain: cur reusable
    __builtin_amdgcn_sched_barrier(0);
    if (t + 2 < NT) {
#pragma unroll
      for (int j = 0; j < 4; j++) {               // stage t+2 into cur slot
        GLOAD16(pA[j] + (size_t)(t + 2) * 64, &As[cur][lo[j]]);
        GLOAD16(pW[j] + (size_t)(t + 2) * 64, &Bs[cur][lo[j]]);
      }
      asm volatile("s_waitcnt vmcnt(8)" ::: "memory");  // t+1 landed; t+2 in flight
    } else if (t + 1 < NT) {
      asm volatile("s_waitcnt vmcnt(0)" ::: "memory");  // last tile: full drain
    }
    if (t + 1 < NT) {
      __builtin_amdgcn_s_barrier();               // publish t+1
      __builtin_amdgcn_sched_barrier(0);
    }
  }

  const float al = ga.alpha;
  if (!RESID && ga.vt) {
    // transposed epilogue: vT[b][gn][t], 4 consecutive tokens per u16x4
#pragma unroll
    for (int i = 0; i < 4; i++)
#pragma unroll
      for (int j = 0; j < 4; j++) {
        int gm0 = m0 + wm + i * 16 + quad * 4;       // token base (mult of 4)
        int gn  = n0 + wn + j * 16 + lane15;         // feature = h*64+d
        int bb2 = gm0 >> 11, tt = gm0 & 2047;
        u16x4 pk;
#pragma unroll
        for (int r = 0; r < 4; r++) pk[r] = f2b(acc[i][j][r] * al);
        *(u16x4*)&ga.C[(size_t)bb2 * 2097152 + (size_t)gn * 2048 + tt] = pk;
      }
  } else {
#pragma unroll
    for (int i = 0; i < 4; i++)
#pragma unroll
      for (int j = 0; j < 4; j++)
#pragma unroll
        for (int r = 0; r < 4; r++) {
          int gm = m0 + wm + i * 16 + quad * 4 + r;  // C/D: row=quad*4+reg
          int gn = n0 + wn + j * 16 + lane15;        //      col=lane&15
          size_t idx = (size_t)gm * N + gn;
          if (RESID) ga.Z[idx] = acc[i][j][r] + ga.R[idx];
          else       ga.C[idx] = f2b(acc[i][j][r] * al);
        }
  }
}

// ---------------------------------------------------------------------------
// Cross flash-attention, no-max softmax. Round-2 version verbatim (102 us,
// VGPR 68, 2 blocks/CU): the round-3 2-deep pipeline pushed VGPR to 140 and
// occupancy to 1 block/CU -> 152 us. Wave-level overlap (2 blocks/CU) is the
// hiding mechanism here; keep register state lean.
//  * K/V LDS: unpadded [64][64], XOR swizzle (byte ^= (row&7)<<4).
//  * softmax scale pre-folded into Q by the QKV GEMM epilogue.
//  * swapped QK^T (mfma(K,Q)=S^T -> P lane-local); PV via 16x16x16bf16_1k
//    (A-frag k=quad*4+j matches swapped C-layout; P never touches LDS).
//  * s_setprio(1) around MFMA clusters.
// ---------------------------------------------------------------------------
#define SWZ(row, bcol) ((row) * 128 + ((bcol) ^ (((row) & 7) << 4)))

__global__ __launch_bounds__(256, 2)
void attn_kernel(const u16* q_a, const u16* k_a, const u16* vt_a,
                 const u16* q_b, const u16* k_b, const u16* vt_b,
                 u16* o_a, u16* o_b) {
  const int br = blockIdx.z;
  const u16* Q  = br ? q_b : q_a;
  const u16* Kp = br ? k_a : k_b;
  const u16* Vp = br ? vt_a : vt_b;
  u16* O = br ? o_b : o_a;
  const int bh = blockIdx.y;
  const int b = bh >> 4, h = bh & 15;
  const int q0 = blockIdx.x * 128;

  const int tid = threadIdx.x, wv = tid >> 6, lane = tid & 63;
  const int lane15 = lane & 15, quad = lane >> 4;

  __shared__ __attribute__((aligned(16))) u16 Ks[2][4096];   // [64][64] swz
  __shared__ __attribute__((aligned(16))) u16 Vt[2][4096];   // [d][key] swz

  const size_t base   = ((size_t)b * L_SEQ) * D_HALF + (size_t)h * HDIM;
  const size_t vbase  = (size_t)b * 2097152 + (size_t)(h * 64) * 2048;

  // staging slots: thread covers 2 u16x8 chunks of each 64x64 tile
  const int c1 = tid + 256;
  const int r0 = tid >> 3, cb0 = (tid & 7) * 16;   // byte col
  const int r1 = c1 >> 3,  cb1 = (c1 & 7) * 16;
  const int wo0 = SWZ(r0, cb0), wo1 = SWZ(r1, cb1);

  // two q fragments per wave: rows q0 + wv*32 + f*16 + lane15
  bf16x8 qf[2][2];
#pragma unroll
  for (int f = 0; f < 2; f++) {
    const int qrow = q0 + wv * 32 + f * 16 + lane15;
#pragma unroll
    for (int c = 0; c < 2; c++)
      qf[f][c] = *(const bf16x8*)&Q[base + (size_t)qrow * D_HALF + c * 32 + quad * 8];
  }

  // stage tile 0
  u16x8 kr0 = *(const u16x8*)&Kp[base + (size_t)r0 * D_HALF + cb0 / 2];
  u16x8 kr1 = *(const u16x8*)&Kp[base + (size_t)r1 * D_HALF + cb1 / 2];
  u16x8 vr0 = *(const u16x8*)&Vp[vbase + (size_t)r0 * 2048 + cb0 / 2];
  u16x8 vr1 = *(const u16x8*)&Vp[vbase + (size_t)r1 * 2048 + cb1 / 2];
  *(u16x8*)((char*)Ks[0] + wo0) = kr0;
  *(u16x8*)((char*)Ks[0] + wo1) = kr1;
  *(u16x8*)((char*)Vt[0] + wo0) = vr0;
  *(u16x8*)((char*)Vt[0] + wo1) = vr1;
  __syncthreads();

  f32x4 oacc[2][4] = {};
  float lsum[2] = {0.f, 0.f};

  for (int it = 0; it < 32; it++) {
    const int cur = it & 1, nxt = cur ^ 1;
    if (it < 31) {
      const int kt = (it + 1) * 64;
      kr0 = *(const u16x8*)&Kp[base + (size_t)(kt + r0) * D_HALF + cb0 / 2];
      kr1 = *(const u16x8*)&Kp[base + (size_t)(kt + r1) * D_HALF + cb1 / 2];
      vr0 = *(const u16x8*)&Vp[vbase + (size_t)r0 * 2048 + kt + cb0 / 2];
      vr1 = *(const u16x8*)&Vp[vbase + (size_t)r1 * 2048 + kt + cb1 / 2];
    }

    const char* kb = (const char*)Ks[cur];
    const char* vb = (const char*)Vt[cur];

    // S^T = K Q^T  (swapped operands: A = K rows, B = Q^T).
    // s[f][nt][r] = S[q = lane15][key = nt*16 + quad*4 + r]
    f32x4 s[2][4];
    __builtin_amdgcn_s_setprio(1);
#pragma unroll
    for (int nt = 0; nt < 4; nt++) {
      const int krow = nt * 16 + lane15;
      bf16x8 kb0 = *(const bf16x8*)(kb + SWZ(krow, quad * 16));
      bf16x8 kb1 = *(const bf16x8*)(kb + SWZ(krow, 64 + quad * 16));
#pragma unroll
      for (int f = 0; f < 2; f++) {
        f32x4 a0 = {};
        a0 = __builtin_amdgcn_mfma_f32_16x16x32_bf16(kb0, qf[f][0], a0, 0, 0, 0);
        a0 = __builtin_amdgcn_mfma_f32_16x16x32_bf16(kb1, qf[f][1], a0, 0, 0, 0);
        s[f][nt] = a0;
      }
    }
    __builtin_amdgcn_s_setprio(0);

    // p = exp2(s)  (scale pre-folded into Q); keys lane-local -> lane-local
    // partial row sum; pack pairs: pa[f][nt] IS the 16x16x16 A-fragment.
    s16x4 pa[2][4];
#pragma unroll
    for (int f = 0; f < 2; f++)
#pragma unroll
      for (int nt = 0; nt < 4; nt++) {
        float p0 = __builtin_amdgcn_exp2f(s[f][nt][0]);
        float p1 = __builtin_amdgcn_exp2f(s[f][nt][1]);
        float p2 = __builtin_amdgcn_exp2f(s[f][nt][2]);
        float p3 = __builtin_amdgcn_exp2f(s[f][nt][3]);
        lsum[f] += (p0 + p1) + (p2 + p3);
        union { uint32_t u[2]; s16x4 v; } cv;
        cv.u[0] = cvt_pk_bf16(p0, p1);
        cv.u[1] = cvt_pk_bf16(p2, p3);
        pa[f][nt] = cv.v;
      }

    // O += P V, K=16 chunks; B-frag: V[16nt+quad*4+j][dt*16+lane15] via b64.
    __builtin_amdgcn_s_setprio(1);
#pragma unroll
    for (int dt = 0; dt < 4; dt++) {
      const int vrow = dt * 16 + lane15;
      s16x4 bv[4];
#pragma unroll
      for (int nt = 0; nt < 4; nt++)
        bv[nt] = *(const s16x4*)(vb + SWZ(vrow, nt * 32 + quad * 8));
#pragma unroll
      for (int f = 0; f < 2; f++) {
        f32x4 t = oacc[f][dt];
#pragma unroll
        for (int nt = 0; nt < 4; nt++)
          t = __builtin_amdgcn_mfma_f32_16x16x16bf16_1k(pa[f][nt], bv[nt], t, 0, 0, 0);
        oacc[f][dt] = t;
      }
    }
    __builtin_amdgcn_s_setprio(0);

    if (it < 31) {
      *(u16x8*)((char*)Ks[nxt] + wo0) = kr0;
      *(u16x8*)((char*)Ks[nxt] + wo1) = kr1;
      *(u16x8*)((char*)Vt[nxt] + wo0) = vr0;
      *(u16x8*)((char*)Vt[nxt] + wo1) = vr1;
    }
    __syncthreads();   // fences: nxt writes before next iter's reads; cur
                       // reads of this iter before iter+1 overwrites cur.
  }

  // finalize: lsum[f] holds this lane's partial for q = lane15; sum the 4
  // quads (xor16+xor32), then redistribute 1/l to C-layout rows (quad*4+r).
#pragma unroll
  for (int f = 0; f < 2; f++) {
    float lt = lsum[f];
    lt += __shfl_xor(lt, 16);
    lt += __shfl_xor(lt, 32);
    lsum[f] = lt;                    // every lane: total for q = lane15
  }
#pragma unroll
  for (int f = 0; f < 2; f++) {
    float linv[4];
#pragma unroll
    for (int r = 0; r < 4; r++)
      linv[r] = 1.0f / __shfl(lsum[f], quad * 4 + r);
#pragma unroll
    for (int dt = 0; dt < 4; dt++)
#pragma unroll
      for (int r = 0; r < 4; r++) {
        float val = oacc[f][dt][r] * linv[r];
        O[base + (size_t)(q0 + wv * 32 + f * 16 + quad * 4 + r) * D_HALF
          + dt * 16 + lane15] = f2b(val);
      }
  }
}

// ---------------------------------------------------------------------------
// LayerNorm over f32 z rows -> f32 out. One block per row.
// ---------------------------------------------------------------------------
__global__ __launch_bounds__(256)
void ln_kernel(const float* zA, const float* zB,
               const float* gA, const float* bA, const float* gB, const float* bB,
               float* out) {
  const int row = blockIdx.x, br = blockIdx.y;
  const float* z = (br ? zB : zA) + (size_t)row * D_HALF;
  const float* g  = br ? gB : gA;
  const float* be = br ? bB : bA;
  float* o = out + (size_t)br * ((size_t)4096 * D_HALF) + (size_t)row * D_HALF;

  float4 v = ((const float4*)z)[threadIdx.x];
  float s  = v.x + v.y + v.z + v.w;
  float s2 = v.x * v.x + v.y * v.y + v.z * v.z + v.w * v.w;
#pragma unroll
  for (int off = 32; off > 0; off >>= 1) {
    s  += __shfl_down(s, off);
    s2 += __shfl_down(s2, off);
  }
  __shared__ float red[8];
  int w = threadIdx.x >> 6, ln = threadIdx.x & 63;
  if (ln == 0) { red[w] = s; red[4 + w] = s2; }
  __syncthreads();
  if (threadIdx.x == 0) {
    red[0] = red[0] + red[1] + red[2] + red[3];
    red[4] = red[4] + red[5] + red[6] + red[7];
  }
  __syncthreads();
  float mu  = red[0] * (1.0f / 1024.0f);
  float var = red[4] * (1.0f / 1024.0f) - mu * mu;
  float rs  = rsqrtf(fmaxf(var, 0.0f) + 1e-5f);

  int col = threadIdx.x * 4;
  float4 gv = ((const float4*)g)[threadIdx.x];
  float4 bv = ((const float4*)be)[threadIdx.x];
  float4 ov;
  ov.x = (v.x - mu) * rs * gv.x + bv.x;
  ov.y = (v.y - mu) * rs * gv.y + bv.y;
  ov.z = (v.z - mu) * rs * gv.z + bv.z;
  ov.w = (v.w - mu) * rs * gv.w + bv.w;
  *(float4*)&o[col] = ov;
}

// ---------------------------------------------------------------------------
extern "C" void kernel_launch(void* const* d_in, const int* in_sizes, int n_in,
                              void* d_out, int out_size, void* d_ws, size_t ws_size,
                              hipStream_t stream) {
  const float* x_a     = (const float*)d_in[0];
  const float* x_b     = (const float*)d_in[1];
  const float* Wq_a    = (const float*)d_in[2];
  const float* Wq_b    = (const float*)d_in[3];
  const float* Wk_a    = (const float*)d_in[4];
  const float* Wk_b    = (const float*)d_in[5];
  const float* Wv_a    = (const float*)d_in[6];
  const float* Wv_b    = (const float*)d_in[7];
  const float* Wo_a    = (const float*)d_in[8];
  const float* Wo_b    = (const float*)d_in[9];
  const float* gamma_a = (const float*)d_in[10];
  const float* beta_a  = (const float*)d_in[11];
  const float* gamma_b = (const float*)d_in[12];
  const float* beta_b  = (const float*)d_in[13];

  // Workspace map (ws = 64 MB = 32M u16; BUF = 4M u16 = 8 MB):
  //   slots 0-5: q_a,k_a,vt_a,q_b,k_b,vt_b (QKV outputs, read by attn)
  //   ws+24M u16 (48 MB): 8 bf16 weights (Wq/Wk/Wv a,b = 12 MB; Wo a,b = 4 MB)
  //   phase 3: z_a/z_b f32 overwrite slots 0-3 (dead after attn)
  // d_out (32 MB) doubles as scratch:
  //   phase 1: xbf_a/xbf_b (16 MB) read by QKV GEMM
  //   phase 2: o_a/o_b (16 MB) written by attn, read by out-proj
  //   ln writes the final f32 output last.
  const size_t BUF = (size_t)4096 * 1024;
  u16* ws   = (u16*)d_ws;
  u16* q_a  = ws + 0 * BUF; u16* k_a  = ws + 1 * BUF; u16* vt_a = ws + 2 * BUF;
  u16* q_b  = ws + 3 * BUF; u16* k_b  = ws + 4 * BUF; u16* vt_b = ws + 5 * BUF;
  u16* wall = ws + 6 * BUF;                    // 8 x 1M-u16 bf16 weights
  float* z_a = (float*)(ws + 0 * BUF);
  float* z_b = (float*)(ws + 2 * BUF);

  u16* xbf_a = (u16*)d_out;
  u16* xbf_b = xbf_a + 4194304;
  u16* o_a   = (u16*)d_out;                    // reuses xbf region (dead)
  u16* o_b   = o_a + 4194304;

  const int M = 4096, N = 1024, K = 1024;

  CArgAll ca;
  ca.src[0] = x_a;  ca.dst[0] = xbf_a;
  ca.src[1] = x_b;  ca.dst[1] = xbf_b;
  ca.src[2] = Wq_a; ca.src[3] = Wk_a; ca.src[4] = Wv_a;
  ca.src[5] = Wq_b; ca.src[6] = Wk_b; ca.src[7] = Wv_b;
  ca.src[8] = Wo_a; ca.src[9] = Wo_b;
  for (int w = 0; w < 8; w++) ca.dst[2 + w] = wall + (size_t)w * 1048576;
  convall<<<dim3(8192), 256, 0, stream>>>(ca);

  GArgs qkv;
  qkv.g[0] = GArg{xbf_a, wall + 0 * 1048576, q_a,  nullptr, nullptr, 0, EXP2_SCALE};
  qkv.g[1] = GArg{xbf_a, wall + 1 * 1048576, k_a,  nullptr, nullptr, 0, 1.0f};
  qkv.g[2] = GArg{xbf_a, wall + 2 * 1048576, vt_a, nullptr, nullptr, 1, 1.0f};
  qkv.g[3] = GArg{xbf_b, wall + 3 * 1048576, q_b,  nullptr, nullptr, 0, EXP2_SCALE};
  qkv.g[4] = GArg{xbf_b, wall + 4 * 1048576, k_b,  nullptr, nullptr, 0, 1.0f};
  qkv.g[5] = GArg{xbf_b, wall + 5 * 1048576, vt_b, nullptr, nullptr, 1, 1.0f};
  gemm_nt<false><<<dim3(8, 32, 6), 256, 0, stream>>>(qkv, M, N, K);

  attn_kernel<<<dim3(16, 32, 2), 256, 0, stream>>>(q_a, k_a, vt_a, q_b, k_b, vt_b, o_a, o_b);

  GArgs op;
  op.g[0] = GArg{o_a, wall + 6 * 1048576, nullptr, x_a, z_a, 0, 1.0f};
  op.g[1] = GArg{o_b, wall + 7 * 1048576, nullptr, x_b, z_b, 0, 1.0f};
  op.g[2] = op.g[0]; op.g[3] = op.g[0]; op.g[4] = op.g[0]; op.g[5] = op.g[0];
  gemm_nt<true><<<dim3(8, 32, 2), 256, 0, stream>>>(op, M, N, K);

  ln_kernel<<<dim3(4096, 2), 256, 0, stream>>>(z_a, z_b, gamma_a, beta_a,
                                               gamma_b, beta_b, (float*)d_out);
}

// Round 5
// 341.706 us; speedup vs baseline: 1.1031x; 1.0008x over previous
//
#include <hip/hip_runtime.h>
#include <cstdint>
#include <cstddef>

typedef __bf16 bf16x8 __attribute__((ext_vector_type(8)));
typedef float f32x4 __attribute__((ext_vector_type(4)));
typedef unsigned short u16x8 __attribute__((ext_vector_type(8)));
typedef unsigned short u16x4 __attribute__((ext_vector_type(4)));
typedef short s16x4 __attribute__((ext_vector_type(4)));
typedef unsigned short u16;

#define L_SEQ 2048
#define D_HALF 1024
#define HDIM 64
// exp(s/sqrt(128)) = exp2(s * EXP2_SCALE); folded into the Q-projection
// epilogue (f32 multiply before the bf16 round -> precision-neutral).
static constexpr float EXP2_SCALE = 0.12751742552639395f; // (1/sqrt(128))*log2(e)

__device__ inline u16 f2b(float f) {
  uint32_t u; __builtin_memcpy(&u, &f, 4);
  u = u + 0x7FFFu + ((u >> 16) & 1u);   // RNE
  return (u16)(u >> 16);
}

// single-instruction f32x2 -> packed bf16 (RNE); no builtin on gfx950.
__device__ inline uint32_t cvt_pk_bf16(float lo, float hi) {
  uint32_t r;
  asm("v_cvt_pk_bf16_f32 %0, %1, %2" : "=v"(r) : "v"(lo), "v"(hi));
  return r;
}

// async global->LDS, 16B per lane; LDS dest is wave-uniform base + lane*16.
#define GLOAD16(gp, lp) __builtin_amdgcn_global_load_lds( \
    (const __attribute__((address_space(1))) unsigned int*)(gp), \
    (__attribute__((address_space(3))) unsigned int*)(lp), 16, 0, 0)

// ---------------------------------------------------------------------------
// Fused f32 -> bf16 converter (x planes + 8 weight matrices, one dispatch).
// id < 4096: x planes (2048 blocks each); else weights (512 blocks each).
// ---------------------------------------------------------------------------
struct CArgAll { const float* src[10]; u16* dst[10]; };
__global__ __launch_bounds__(256)
void convall(CArgAll a) {
  const int id = blockIdx.x;
  const float* s; u16* d; int blk;
  if (id < 4096) { int p = id >> 11; blk = id & 2047; s = a.src[p]; d = a.dst[p]; }
  else { int w = (id - 4096) >> 9; blk = (id - 4096) & 511; s = a.src[2 + w]; d = a.dst[2 + w]; }
  size_t i = ((size_t)blk * 256 + threadIdx.x) * 8;
  float4 v0 = *(const float4*)(s + i);
  float4 v1 = *(const float4*)(s + i + 4);
  u16x8 p;
  p[0] = f2b(v0.x); p[1] = f2b(v0.y); p[2] = f2b(v0.z); p[3] = f2b(v0.w);
  p[4] = f2b(v1.x); p[5] = f2b(v1.y); p[6] = f2b(v1.z); p[7] = f2b(v1.w);
  *(u16x8*)&d[i] = p;
}

// ---------------------------------------------------------------------------
// Batched GEMM: C[m][n] = sum_k A[m][k] * W[n][k]  (torch-Linear x@W.T form).
// m97-faithful structure (measured best: round-3 non-attn 224 vs 238-240 for
// both explicit-dbuf variants): SINGLE 32KB LDS buffer, global_load_lds
// width=16 staged between two __syncthreads per K-step, no launch_bounds
// waves cap. Source-XOR swizzle + matching read-XOR (rule 21 both-sides).
// NEW: 1D grid, z-INNERMOST decode + bijective XCD chunk swizzle (T1).
// The 3 QKV GEMMs of one branch share the same A panel; z-innermost makes
// the sharers dispatch-adjacent (same XCD, same time -> L2 hit), and XCD
// chunking keeps a contiguous (x,y) neighborhood per L2. nwg%8==0 in both
// dispatches -> simple bijective form.
// alpha: folded scalar epilogue (softmax scale -> Q). RESID: + f32 residual
// -> f32 z. vt: transposed epilogue to vT[b][h*64+d][t].
// ---------------------------------------------------------------------------
struct GArg { const u16* A; const u16* W; u16* C; const float* R; float* Z;
              int vt; float alpha; };
struct GArgs { GArg g[6]; };

template <bool RESID>
__global__ __launch_bounds__(256)
void gemm_nt(GArgs args, int N, int K, int ZN) {
  // bijective XCD swizzle (nwg % 8 == 0), then z-innermost decode.
  const int nwg = gridDim.x;
  const int q8 = nwg >> 3;
  const int bid = ((int)blockIdx.x & 7) * q8 + ((int)blockIdx.x >> 3);
  const int z = bid % ZN;
  const int rem = bid / ZN;
  const int nx = N >> 7;
  const int bx = rem % nx, by = rem / nx;

  GArg ga = args.g[z];
  __shared__ __attribute__((aligned(16))) u16 As[8192];   // [128][64] linear
  __shared__ __attribute__((aligned(16))) u16 Bs[8192];

  const int tid = threadIdx.x;
  const int wv = tid >> 6, lane = tid & 63;
  const int lane15 = lane & 15, quad = lane >> 4;
  const int m0 = by * 128, n0 = bx * 128;
  const int wm = (wv >> 1) * 64, wn = (wv & 1) * 64;

  // staging: wave issue j covers LDS rows wv*32+j*8 .. +7 (1KB linear).
  // lane -> row wv*32+j*8+(lane>>3), physical chunk lane&7; source chunk
  // XOR-swizzled so the read-side XOR recovers logical order.
  const int srow = lane >> 3;
  const int scol = ((lane & 7) ^ srow) * 8;      // swizzled source u16 col

  const u16* pA[4]; const u16* pW[4]; int lo[4];
#pragma unroll
  for (int j = 0; j < 4; j++) {
    int r = wv * 32 + j * 8;
    pA[j] = ga.A + (size_t)(m0 + r + srow) * K + scol;
    pW[j] = ga.W + (size_t)(n0 + r + srow) * K + scol;
    lo[j] = r * 64;
  }

  f32x4 acc[4][4] = {};
  const int swz = (lane15 & 7) << 4;             // read-side XOR (bytes)

  for (int k0 = 0; k0 < K; k0 += 64) {
    __syncthreads();     // WAR: previous tile's ds_reads drained
#pragma unroll
    for (int j = 0; j < 4; j++) {
      GLOAD16(pA[j] + k0, &As[lo[j]]);
      GLOAD16(pW[j] + k0, &Bs[lo[j]]);
    }
    __syncthreads();     // vmcnt(0) drain -> tile resident
    const char* ab = (const char*)As;
    const char* bb = (const char*)Bs;
#pragma unroll
    for (int kk = 0; kk < 2; kk++) {
      const int cb = kk * 64 + quad * 16;
      bf16x8 af[4], bw[4];
#pragma unroll
      for (int i = 0; i < 4; i++)
        af[i] = *(const bf16x8*)(ab + (wm + i * 16 + lane15) * 128 + (cb ^ swz));
#pragma unroll
      for (int j = 0; j < 4; j++)
        bw[j] = *(const bf16x8*)(bb + (wn + j * 16 + lane15) * 128 + (cb ^ swz));
#pragma unroll
      for (int i = 0; i < 4; i++)
#pragma unroll
        for (int j = 0; j < 4; j++)
          acc[i][j] = __builtin_amdgcn_mfma_f32_16x16x32_bf16(af[i], bw[j], acc[i][j], 0, 0, 0);
    }
  }

  const float al = ga.alpha;
  if (!RESID && ga.vt) {
    // transposed epilogue: vT[b][gn][t], 4 consecutive tokens per u16x4
#pragma unroll
    for (int i = 0; i < 4; i++)
#pragma unroll
      for (int j = 0; j < 4; j++) {
        int gm0 = m0 + wm + i * 16 + quad * 4;       // token base (mult of 4)
        int gn  = n0 + wn + j * 16 + lane15;         // feature = h*64+d
        int bb2 = gm0 >> 11, tt = gm0 & 2047;
        u16x4 pk;
#pragma unroll
        for (int r = 0; r < 4; r++) pk[r] = f2b(acc[i][j][r] * al);
        *(u16x4*)&ga.C[(size_t)bb2 * 2097152 + (size_t)gn * 2048 + tt] = pk;
      }
  } else {
#pragma unroll
    for (int i = 0; i < 4; i++)
#pragma unroll
      for (int j = 0; j < 4; j++)
#pragma unroll
        for (int r = 0; r < 4; r++) {
          int gm = m0 + wm + i * 16 + quad * 4 + r;  // C/D: row=quad*4+reg
          int gn = n0 + wn + j * 16 + lane15;        //      col=lane&15
          size_t idx = (size_t)gm * N + gn;
          if (RESID) ga.Z[idx] = acc[i][j][r] + ga.R[idx];
          else       ga.C[idx] = f2b(acc[i][j][r] * al);
        }
  }
}

// ---------------------------------------------------------------------------
// Cross flash-attention, no-max softmax. Round-2 version verbatim (102 us,
// VGPR 68): the 2-deep pipeline attempt pushed VGPR to 140 and occupancy to
// 1 block/CU -> 152 us. Wave-level overlap is the hiding mechanism here;
// keep register state lean.
//  * K/V LDS: unpadded [64][64], XOR swizzle (byte ^= (row&7)<<4).
//  * softmax scale pre-folded into Q by the QKV GEMM epilogue.
//  * swapped QK^T (mfma(K,Q)=S^T -> P lane-local); PV via 16x16x16bf16_1k
//    (A-frag k=quad*4+j matches swapped C-layout; P never touches LDS).
//  * s_setprio(1) around MFMA clusters.
// ---------------------------------------------------------------------------
#define SWZ(row, bcol) ((row) * 128 + ((bcol) ^ (((row) & 7) << 4)))

__global__ __launch_bounds__(256, 2)
void attn_kernel(const u16* q_a, const u16* k_a, const u16* vt_a,
                 const u16* q_b, const u16* k_b, const u16* vt_b,
                 u16* o_a, u16* o_b) {
  const int br = blockIdx.z;
  const u16* Q  = br ? q_b : q_a;
  const u16* Kp = br ? k_a : k_b;
  const u16* Vp = br ? vt_a : vt_b;
  u16* O = br ? o_b : o_a;
  const int bh = blockIdx.y;
  const int b = bh >> 4, h = bh & 15;
  const int q0 = blockIdx.x * 128;

  const int tid = threadIdx.x, wv = tid >> 6, lane = tid & 63;
  const int lane15 = lane & 15, quad = lane >> 4;

  __shared__ __attribute__((aligned(16))) u16 Ks[2][4096];   // [64][64] swz
  __shared__ __attribute__((aligned(16))) u16 Vt[2][4096];   // [d][key] swz

  const size_t base   = ((size_t)b * L_SEQ) * D_HALF + (size_t)h * HDIM;
  const size_t vbase  = (size_t)b * 2097152 + (size_t)(h * 64) * 2048;

  // staging slots: thread covers 2 u16x8 chunks of each 64x64 tile
  const int c1 = tid + 256;
  const int r0 = tid >> 3, cb0 = (tid & 7) * 16;   // byte col
  const int r1 = c1 >> 3,  cb1 = (c1 & 7) * 16;
  const int wo0 = SWZ(r0, cb0), wo1 = SWZ(r1, cb1);

  // two q fragments per wave: rows q0 + wv*32 + f*16 + lane15
  bf16x8 qf[2][2];
#pragma unroll
  for (int f = 0; f < 2; f++) {
    const int qrow = q0 + wv * 32 + f * 16 + lane15;
#pragma unroll
    for (int c = 0; c < 2; c++)
      qf[f][c] = *(const bf16x8*)&Q[base + (size_t)qrow * D_HALF + c * 32 + quad * 8];
  }

  // stage tile 0
  u16x8 kr0 = *(const u16x8*)&Kp[base + (size_t)r0 * D_HALF + cb0 / 2];
  u16x8 kr1 = *(const u16x8*)&Kp[base + (size_t)r1 * D_HALF + cb1 / 2];
  u16x8 vr0 = *(const u16x8*)&Vp[vbase + (size_t)r0 * 2048 + cb0 / 2];
  u16x8 vr1 = *(const u16x8*)&Vp[vbase + (size_t)r1 * 2048 + cb1 / 2];
  *(u16x8*)((char*)Ks[0] + wo0) = kr0;
  *(u16x8*)((char*)Ks[0] + wo1) = kr1;
  *(u16x8*)((char*)Vt[0] + wo0) = vr0;
  *(u16x8*)((char*)Vt[0] + wo1) = vr1;
  __syncthreads();

  f32x4 oacc[2][4] = {};
  float lsum[2] = {0.f, 0.f};

  for (int it = 0; it < 32; it++) {
    const int cur = it & 1, nxt = cur ^ 1;
    if (it < 31) {
      const int kt = (it + 1) * 64;
      kr0 = *(const u16x8*)&Kp[base + (size_t)(kt + r0) * D_HALF + cb0 / 2];
      kr1 = *(const u16x8*)&Kp[base + (size_t)(kt + r1) * D_HALF + cb1 / 2];
      vr0 = *(const u16x8*)&Vp[vbase + (size_t)r0 * 2048 + kt + cb0 / 2];
      vr1 = *(const u16x8*)&Vp[vbase + (size_t)r1 * 2048 + kt + cb1 / 2];
    }

    const char* kb = (const char*)Ks[cur];
    const char* vb = (const char*)Vt[cur];

    // S^T = K Q^T  (swapped operands: A = K rows, B = Q^T).
    // s[f][nt][r] = S[q = lane15][key = nt*16 + quad*4 + r]
    f32x4 s[2][4];
    __builtin_amdgcn_s_setprio(1);
#pragma unroll
    for (int nt = 0; nt < 4; nt++) {
      const int krow = nt * 16 + lane15;
      bf16x8 kb0 = *(const bf16x8*)(kb + SWZ(krow, quad * 16));
      bf16x8 kb1 = *(const bf16x8*)(kb + SWZ(krow, 64 + quad * 16));
#pragma unroll
      for (int f = 0; f < 2; f++) {
        f32x4 a0 = {};
        a0 = __builtin_amdgcn_mfma_f32_16x16x32_bf16(kb0, qf[f][0], a0, 0, 0, 0);
        a0 = __builtin_amdgcn_mfma_f32_16x16x32_bf16(kb1, qf[f][1], a0, 0, 0, 0);
        s[f][nt] = a0;
      }
    }
    __builtin_amdgcn_s_setprio(0);

    // p = exp2(s)  (scale pre-folded into Q); keys lane-local -> lane-local
    // partial row sum; pack pairs: pa[f][nt] IS the 16x16x16 A-fragment.
    s16x4 pa[2][4];
#pragma unroll
    for (int f = 0; f < 2; f++)
#pragma unroll
      for (int nt = 0; nt < 4; nt++) {
        float p0 = __builtin_amdgcn_exp2f(s[f][nt][0]);
        float p1 = __builtin_amdgcn_exp2f(s[f][nt][1]);
        float p2 = __builtin_amdgcn_exp2f(s[f][nt][2]);
        float p3 = __builtin_amdgcn_exp2f(s[f][nt][3]);
        lsum[f] += (p0 + p1) + (p2 + p3);
        union { uint32_t u[2]; s16x4 v; } cv;
        cv.u[0] = cvt_pk_bf16(p0, p1);
        cv.u[1] = cvt_pk_bf16(p2, p3);
        pa[f][nt] = cv.v;
      }

    // O += P V, K=16 chunks; B-frag: V[16nt+quad*4+j][dt*16+lane15] via b64.
    __builtin_amdgcn_s_setprio(1);
#pragma unroll
    for (int dt = 0; dt < 4; dt++) {
      const int vrow = dt * 16 + lane15;
      s16x4 bv[4];
#pragma unroll
      for (int nt = 0; nt < 4; nt++)
        bv[nt] = *(const s16x4*)(vb + SWZ(vrow, nt * 32 + quad * 8));
#pragma unroll
      for (int f = 0; f < 2; f++) {
        f32x4 t = oacc[f][dt];
#pragma unroll
        for (int nt = 0; nt < 4; nt++)
          t = __builtin_amdgcn_mfma_f32_16x16x16bf16_1k(pa[f][nt], bv[nt], t, 0, 0, 0);
        oacc[f][dt] = t;
      }
    }
    __builtin_amdgcn_s_setprio(0);

    if (it < 31) {
      *(u16x8*)((char*)Ks[nxt] + wo0) = kr0;
      *(u16x8*)((char*)Ks[nxt] + wo1) = kr1;
      *(u16x8*)((char*)Vt[nxt] + wo0) = vr0;
      *(u16x8*)((char*)Vt[nxt] + wo1) = vr1;
    }
    __syncthreads();   // fences: nxt writes before next iter's reads; cur
                       // reads of this iter before iter+1 overwrites cur.
  }

  // finalize: lsum[f] holds this lane's partial for q = lane15; sum the 4
  // quads (xor16+xor32), then redistribute 1/l to C-layout rows (quad*4+r).
#pragma unroll
  for (int f = 0; f < 2; f++) {
    float lt = lsum[f];
    lt += __shfl_xor(lt, 16);
    lt += __shfl_xor(lt, 32);
    lsum[f] = lt;                    // every lane: total for q = lane15
  }
#pragma unroll
  for (int f = 0; f < 2; f++) {
    float linv[4];
#pragma unroll
    for (int r = 0; r < 4; r++)
      linv[r] = 1.0f / __shfl(lsum[f], quad * 4 + r);
#pragma unroll
    for (int dt = 0; dt < 4; dt++)
#pragma unroll
      for (int r = 0; r < 4; r++) {
        float val = oacc[f][dt][r] * linv[r];
        O[base + (size_t)(q0 + wv * 32 + f * 16 + quad * 4 + r) * D_HALF
          + dt * 16 + lane15] = f2b(val);
      }
  }
}

// ---------------------------------------------------------------------------
// LayerNorm over f32 z rows -> f32 out. One block per row.
// ---------------------------------------------------------------------------
__global__ __launch_bounds__(256)
void ln_kernel(const float* zA, const float* zB,
               const float* gA, const float* bA, const float* gB, const float* bB,
               float* out) {
  const int row = blockIdx.x, br = blockIdx.y;
  const float* z = (br ? zB : zA) + (size_t)row * D_HALF;
  const float* g  = br ? gB : gA;
  const float* be = br ? bB : bA;
  float* o = out + (size_t)br * ((size_t)4096 * D_HALF) + (size_t)row * D_HALF;

  float4 v = ((const float4*)z)[threadIdx.x];
  float s  = v.x + v.y + v.z + v.w;
  float s2 = v.x * v.x + v.y * v.y + v.z * v.z + v.w * v.w;
#pragma unroll
  for (int off = 32; off > 0; off >>= 1) {
    s  += __shfl_down(s, off);
    s2 += __shfl_down(s2, off);
  }
  __shared__ float red[8];
  int w = threadIdx.x >> 6, ln = threadIdx.x & 63;
  if (ln == 0) { red[w] = s; red[4 + w] = s2; }
  __syncthreads();
  if (threadIdx.x == 0) {
    red[0] = red[0] + red[1] + red[2] + red[3];
    red[4] = red[4] + red[5] + red[6] + red[7];
  }
  __syncthreads();
  float mu  = red[0] * (1.0f / 1024.0f);
  float var = red[4] * (1.0f / 1024.0f) - mu * mu;
  float rs  = rsqrtf(fmaxf(var, 0.0f) + 1e-5f);

  int col = threadIdx.x * 4;
  float4 gv = ((const float4*)g)[threadIdx.x];
  float4 bv = ((const float4*)be)[threadIdx.x];
  float4 ov;
  ov.x = (v.x - mu) * rs * gv.x + bv.x;
  ov.y = (v.y - mu) * rs * gv.y + bv.y;
  ov.z = (v.z - mu) * rs * gv.z + bv.z;
  ov.w = (v.w - mu) * rs * gv.w + bv.w;
  *(float4*)&o[col] = ov;
}

// ---------------------------------------------------------------------------
extern "C" void kernel_launch(void* const* d_in, const int* in_sizes, int n_in,
                              void* d_out, int out_size, void* d_ws, size_t ws_size,
                              hipStream_t stream) {
  const float* x_a     = (const float*)d_in[0];
  const float* x_b     = (const float*)d_in[1];
  const float* Wq_a    = (const float*)d_in[2];
  const float* Wq_b    = (const float*)d_in[3];
  const float* Wk_a    = (const float*)d_in[4];
  const float* Wk_b    = (const float*)d_in[5];
  const float* Wv_a    = (const float*)d_in[6];
  const float* Wv_b    = (const float*)d_in[7];
  const float* Wo_a    = (const float*)d_in[8];
  const float* Wo_b    = (const float*)d_in[9];
  const float* gamma_a = (const float*)d_in[10];
  const float* beta_a  = (const float*)d_in[11];
  const float* gamma_b = (const float*)d_in[12];
  const float* beta_b  = (const float*)d_in[13];

  // Workspace map (ws = 64 MB = 32M u16; BUF = 4M u16 = 8 MB):
  //   slots 0-5: q_a,k_a,vt_a,q_b,k_b,vt_b (QKV outputs, read by attn)
  //   ws+24M u16 (48 MB): 8 bf16 weights (Wq/Wk/Wv a,b = 12 MB; Wo a,b = 4 MB)
  //   phase 3: z_a/z_b f32 overwrite slots 0-3 (dead after attn)
  // d_out (32 MB) doubles as scratch:
  //   phase 1: xbf_a/xbf_b (16 MB) read by QKV GEMM
  //   phase 2: o_a/o_b (16 MB) written by attn, read by out-proj
  //   ln writes the final f32 output last.
  const size_t BUF = (size_t)4096 * 1024;
  u16* ws   = (u16*)d_ws;
  u16* q_a  = ws + 0 * BUF; u16* k_a  = ws + 1 * BUF; u16* vt_a = ws + 2 * BUF;
  u16* q_b  = ws + 3 * BUF; u16* k_b  = ws + 4 * BUF; u16* vt_b = ws + 5 * BUF;
  u16* wall = ws + 6 * BUF;                    // 8 x 1M-u16 bf16 weights
  float* z_a = (float*)(ws + 0 * BUF);
  float* z_b = (float*)(ws + 2 * BUF);

  u16* xbf_a = (u16*)d_out;
  u16* xbf_b = xbf_a + 4194304;
  u16* o_a   = (u16*)d_out;                    // reuses xbf region (dead)
  u16* o_b   = o_a + 4194304;

  const int N = 1024, K = 1024;

  CArgAll ca;
  ca.src[0] = x_a;  ca.dst[0] = xbf_a;
  ca.src[1] = x_b;  ca.dst[1] = xbf_b;
  ca.src[2] = Wq_a; ca.src[3] = Wk_a; ca.src[4] = Wv_a;
  ca.src[5] = Wq_b; ca.src[6] = Wk_b; ca.src[7] = Wv_b;
  ca.src[8] = Wo_a; ca.src[9] = Wo_b;
  for (int w = 0; w < 8; w++) ca.dst[2 + w] = wall + (size_t)w * 1048576;
  convall<<<dim3(8192), 256, 0, stream>>>(ca);

  GArgs qkv;
  qkv.g[0] = GArg{xbf_a, wall + 0 * 1048576, q_a,  nullptr, nullptr, 0, EXP2_SCALE};
  qkv.g[1] = GArg{xbf_a, wall + 1 * 1048576, k_a,  nullptr, nullptr, 0, 1.0f};
  qkv.g[2] = GArg{xbf_a, wall + 2 * 1048576, vt_a, nullptr, nullptr, 1, 1.0f};
  qkv.g[3] = GArg{xbf_b, wall + 3 * 1048576, q_b,  nullptr, nullptr, 0, EXP2_SCALE};
  qkv.g[4] = GArg{xbf_b, wall + 4 * 1048576, k_b,  nullptr, nullptr, 0, 1.0f};
  qkv.g[5] = GArg{xbf_b, wall + 5 * 1048576, vt_b, nullptr, nullptr, 1, 1.0f};
  // 1536 blocks: 8 x-tiles * 32 y-tiles * 6 z, z innermost, XCD-swizzled.
  gemm_nt<false><<<dim3(8 * 32 * 6), 256, 0, stream>>>(qkv, N, K, 6);

  attn_kernel<<<dim3(16, 32, 2), 256, 0, stream>>>(q_a, k_a, vt_a, q_b, k_b, vt_b, o_a, o_b);

  GArgs op;
  op.g[0] = GArg{o_a, wall + 6 * 1048576, nullptr, x_a, z_a, 0, 1.0f};
  op.g[1] = GArg{o_b, wall + 7 * 1048576, nullptr, x_b, z_b, 0, 1.0f};
  op.g[2] = op.g[0]; op.g[3] = op.g[0]; op.g[4] = op.g[0]; op.g[5] = op.g[0];
  gemm_nt<true><<<dim3(8 * 32 * 2), 256, 0, stream>>>(op, N, K, 2);

  ln_kernel<<<dim3(4096, 2), 256, 0, stream>>>(z_a, z_b, gamma_a, beta_a,
                                               gamma_b, beta_b, (float*)d_out);
}

// Round 7
// 326.078 us; speedup vs baseline: 1.1560x; 1.0479x over previous
//
#include <hip/hip_runtime.h>
#include <cstdint>
#include <cstddef>

typedef __bf16 bf16x8 __attribute__((ext_vector_type(8)));
typedef float f32x4 __attribute__((ext_vector_type(4)));
typedef unsigned short u16x8 __attribute__((ext_vector_type(8)));
typedef unsigned short u16x4 __attribute__((ext_vector_type(4)));
typedef short s16x4 __attribute__((ext_vector_type(4)));
typedef unsigned short u16;

#define L_SEQ 2048
#define D_HALF 1024
#define HDIM 64
// exp(s/sqrt(128)) = exp2(s * EXP2_SCALE); folded into the Q-projection
// epilogue (f32 multiply before the bf16 round -> precision-neutral).
static constexpr float EXP2_SCALE = 0.12751742552639395f; // (1/sqrt(128))*log2(e)

__device__ inline u16 f2b(float f) {
  uint32_t u; __builtin_memcpy(&u, &f, 4);
  u = u + 0x7FFFu + ((u >> 16) & 1u);   // RNE
  return (u16)(u >> 16);
}

// single-instruction f32x2 -> packed bf16 (RNE); no builtin on gfx950.
__device__ inline uint32_t cvt_pk_bf16(float lo, float hi) {
  uint32_t r;
  asm("v_cvt_pk_bf16_f32 %0, %1, %2" : "=v"(r) : "v"(lo), "v"(hi));
  return r;
}

// async global->LDS, 16B per lane; LDS dest is wave-uniform base + lane*16.
#define GLOAD16(gp, lp) __builtin_amdgcn_global_load_lds( \
    (const __attribute__((address_space(1))) unsigned int*)(gp), \
    (__attribute__((address_space(3))) unsigned int*)(lp), 16, 0, 0)

// ---------------------------------------------------------------------------
// Fused f32 -> bf16 converter (x planes + 8 weight matrices, one dispatch).
// id < 4096: x planes (2048 blocks each); else weights (512 blocks each).
// ---------------------------------------------------------------------------
struct CArgAll { const float* src[10]; u16* dst[10]; };
__global__ __launch_bounds__(256)
void convall(CArgAll a) {
  const int id = blockIdx.x;
  const float* s; u16* d; int blk;
  if (id < 4096) { int p = id >> 11; blk = id & 2047; s = a.src[p]; d = a.dst[p]; }
  else { int w = (id - 4096) >> 9; blk = (id - 4096) & 511; s = a.src[2 + w]; d = a.dst[2 + w]; }
  size_t i = ((size_t)blk * 256 + threadIdx.x) * 8;
  float4 v0 = *(const float4*)(s + i);
  float4 v1 = *(const float4*)(s + i + 4);
  u16x8 p;
  p[0] = f2b(v0.x); p[1] = f2b(v0.y); p[2] = f2b(v0.z); p[3] = f2b(v0.w);
  p[4] = f2b(v1.x); p[5] = f2b(v1.y); p[6] = f2b(v1.z); p[7] = f2b(v1.w);
  *(u16x8*)&d[i] = p;
}

// ---------------------------------------------------------------------------
// Batched GEMM: C[m][n] = sum_k A[m][k] * W[n][k]  (torch-Linear x@W.T form).
// Round-3 measured-best form (non-attn 224.4 us): m97 single 32KB LDS buffer,
// global_load_lds width=16 between two __syncthreads per K-step, plain 3D
// grid dim3(8,32,6) with z OUTER (x-innermost HW order: 8 consecutive blocks
// share one A-panel and one weight matrix -> best L2 set). The z-innermost
// XCD remap (round 5) measured -15 us: REVERTED.
// Source-XOR swizzle on gload src + matching read-XOR (rule 21 both-sides).
// alpha: folded scalar epilogue (softmax scale -> Q). RESID: + f32 residual
// -> f32 z. vt: transposed epilogue to vT[b][h*64+d][t].
// ---------------------------------------------------------------------------
struct GArg { const u16* A; const u16* W; u16* C; const float* R; float* Z;
              int vt; float alpha; };
struct GArgs { GArg g[6]; };

template <bool RESID>
__global__ __launch_bounds__(256)
void gemm_nt(GArgs args, int N, int K) {
  GArg ga = args.g[blockIdx.z];
  __shared__ __attribute__((aligned(16))) u16 As[8192];   // [128][64] linear
  __shared__ __attribute__((aligned(16))) u16 Bs[8192];

  const int tid = threadIdx.x;
  const int wv = tid >> 6, lane = tid & 63;
  const int lane15 = lane & 15, quad = lane >> 4;
  const int m0 = blockIdx.y * 128, n0 = blockIdx.x * 128;
  const int wm = (wv >> 1) * 64, wn = (wv & 1) * 64;

  // staging: wave issue j covers LDS rows wv*32+j*8 .. +7 (1KB linear).
  // lane -> row wv*32+j*8+(lane>>3), physical chunk lane&7; source chunk
  // XOR-swizzled so the read-side XOR recovers logical order.
  const int srow = lane >> 3;
  const int scol = ((lane & 7) ^ srow) * 8;      // swizzled source u16 col

  const u16* pA[4]; const u16* pW[4]; int lo[4];
#pragma unroll
  for (int j = 0; j < 4; j++) {
    int r = wv * 32 + j * 8;
    pA[j] = ga.A + (size_t)(m0 + r + srow) * K + scol;
    pW[j] = ga.W + (size_t)(n0 + r + srow) * K + scol;
    lo[j] = r * 64;
  }

  f32x4 acc[4][4] = {};
  const int swz = (lane15 & 7) << 4;             // read-side XOR (bytes)

  for (int k0 = 0; k0 < K; k0 += 64) {
    __syncthreads();     // WAR: previous tile's ds_reads drained
#pragma unroll
    for (int j = 0; j < 4; j++) {
      GLOAD16(pA[j] + k0, &As[lo[j]]);
      GLOAD16(pW[j] + k0, &Bs[lo[j]]);
    }
    __syncthreads();     // vmcnt(0) drain -> tile resident
    const char* ab = (const char*)As;
    const char* bb = (const char*)Bs;
#pragma unroll
    for (int kk = 0; kk < 2; kk++) {
      const int cb = kk * 64 + quad * 16;
      bf16x8 af[4], bw[4];
#pragma unroll
      for (int i = 0; i < 4; i++)
        af[i] = *(const bf16x8*)(ab + (wm + i * 16 + lane15) * 128 + (cb ^ swz));
#pragma unroll
      for (int j = 0; j < 4; j++)
        bw[j] = *(const bf16x8*)(bb + (wn + j * 16 + lane15) * 128 + (cb ^ swz));
#pragma unroll
      for (int i = 0; i < 4; i++)
#pragma unroll
        for (int j = 0; j < 4; j++)
          acc[i][j] = __builtin_amdgcn_mfma_f32_16x16x32_bf16(af[i], bw[j], acc[i][j], 0, 0, 0);
    }
  }

  const float al = ga.alpha;
  if (!RESID && ga.vt) {
    // transposed epilogue: vT[b][gn][t], 4 consecutive tokens per u16x4
#pragma unroll
    for (int i = 0; i < 4; i++)
#pragma unroll
      for (int j = 0; j < 4; j++) {
        int gm0 = m0 + wm + i * 16 + quad * 4;       // token base (mult of 4)
        int gn  = n0 + wn + j * 16 + lane15;         // feature = h*64+d
        int bb2 = gm0 >> 11, tt = gm0 & 2047;
        u16x4 pk;
#pragma unroll
        for (int r = 0; r < 4; r++) pk[r] = f2b(acc[i][j][r] * al);
        *(u16x4*)&ga.C[(size_t)bb2 * 2097152 + (size_t)gn * 2048 + tt] = pk;
      }
  } else {
#pragma unroll
    for (int i = 0; i < 4; i++)
#pragma unroll
      for (int j = 0; j < 4; j++)
#pragma unroll
        for (int r = 0; r < 4; r++) {
          int gm = m0 + wm + i * 16 + quad * 4 + r;  // C/D: row=quad*4+reg
          int gn = n0 + wn + j * 16 + lane15;        //      col=lane&15
          size_t idx = (size_t)gm * N + gn;
          if (RESID) ga.Z[idx] = acc[i][j][r] + ga.R[idx];
          else       ga.C[idx] = f2b(acc[i][j][r] * al);
        }
  }
}

// ---------------------------------------------------------------------------
// Cross flash-attention, no-max softmax. K/V staging via global_load_lds
// width=16 (async direct-to-LDS). The XOR swizzle moves to the SOURCE
// address (rule 21: gload_lds writes linearly; src chunk =
// (lane&7)^(lane>>3), identical to the GEMM's proven pattern) so the read
// side is byte-for-byte unchanged. Loads issue at iter TOP into the nxt
// buffer (prev barrier guarantees all reads of nxt done); the end-of-iter
// __syncthreads vmcnt-drain is the completion guarantee. Deletes 4 global
// loads + 4 ds_writes + 16 staging VGPRs per thread-iter; removes the
// pre-barrier vmcnt->ds_write tail stall and the ds_write share of bank
// conflicts.
// Retained: swapped QK^T (mfma(K,Q)=S^T -> P lane-local), PV via
// 16x16x16bf16_1k (P never touches LDS), scale pre-folded into Q, setprio.
// ---------------------------------------------------------------------------
#define SWZ(row, bcol) ((row) * 128 + ((bcol) ^ (((row) & 7) << 4)))

__global__ __launch_bounds__(256, 2)
void attn_kernel(const u16* q_a, const u16* k_a, const u16* vt_a,
                 const u16* q_b, const u16* k_b, const u16* vt_b,
                 u16* o_a, u16* o_b) {
  const int br = blockIdx.z;
  const u16* Q  = br ? q_b : q_a;
  const u16* Kp = br ? k_a : k_b;
  const u16* Vp = br ? vt_a : vt_b;
  u16* O = br ? o_b : o_a;
  const int bh = blockIdx.y;
  const int b = bh >> 4, h = bh & 15;
  const int q0 = blockIdx.x * 128;

  const int tid = threadIdx.x, wv = tid >> 6, lane = tid & 63;
  const int lane15 = lane & 15, quad = lane >> 4;

  __shared__ __attribute__((aligned(16))) u16 Ks[2][4096];   // [64][64] swz
  __shared__ __attribute__((aligned(16))) u16 Vt[2][4096];   // [d][key] swz

  const size_t base   = ((size_t)b * L_SEQ) * D_HALF + (size_t)h * HDIM;
  const size_t vbase  = (size_t)b * 2097152 + (size_t)(h * 64) * 2048;

  // gload_lds staging: wave wv covers rows wv*8..+7 (1KB) and 32+wv*8..+7.
  // Source col pre-swizzled: chunk = (lane&7) ^ (lane>>3); row%8 = lane>>3
  // for both row groups -> read-side SWZ() recovers logical order.
  const int lrow = lane >> 3;                    // 0..7
  const int sc  = ((lane & 7) ^ lrow) * 8;       // source u16 col
  const int row0 = wv * 8 + lrow;
  const int row1 = 32 + wv * 8 + lrow;
  const int ldo0 = (wv * 8) * 128;               // wave-uniform LDS byte base
  const int ldo1 = (32 + wv * 8) * 128;

  // two q fragments per wave: rows q0 + wv*32 + f*16 + lane15
  bf16x8 qf[2][2];
#pragma unroll
  for (int f = 0; f < 2; f++) {
    const int qrow = q0 + wv * 32 + f * 16 + lane15;
#pragma unroll
    for (int c = 0; c < 2; c++)
      qf[f][c] = *(const bf16x8*)&Q[base + (size_t)qrow * D_HALF + c * 32 + quad * 8];
  }

  // stage tile 0 (async -> Ks[0]/Vt[0]; __syncthreads drains vmcnt)
  GLOAD16(Kp + base + (size_t)row0 * D_HALF + sc, (char*)Ks[0] + ldo0);
  GLOAD16(Kp + base + (size_t)row1 * D_HALF + sc, (char*)Ks[0] + ldo1);
  GLOAD16(Vp + vbase + (size_t)row0 * 2048 + sc,  (char*)Vt[0] + ldo0);
  GLOAD16(Vp + vbase + (size_t)row1 * 2048 + sc,  (char*)Vt[0] + ldo1);
  __syncthreads();

  f32x4 oacc[2][4] = {};
  float lsum[2] = {0.f, 0.f};

  for (int it = 0; it < 32; it++) {
    const int cur = it & 1, nxt = cur ^ 1;
    if (it < 31) {
      // async-stage tile it+1 into nxt; completes at this iter's barrier.
      const int kt = (it + 1) * 64;
      GLOAD16(Kp + base + (size_t)(kt + row0) * D_HALF + sc, (char*)Ks[nxt] + ldo0);
      GLOAD16(Kp + base + (size_t)(kt + row1) * D_HALF + sc, (char*)Ks[nxt] + ldo1);
      GLOAD16(Vp + vbase + (size_t)row0 * 2048 + kt + sc,    (char*)Vt[nxt] + ldo0);
      GLOAD16(Vp + vbase + (size_t)row1 * 2048 + kt + sc,    (char*)Vt[nxt] + ldo1);
    }

    const char* kb = (const char*)Ks[cur];
    const char* vb = (const char*)Vt[cur];

    // S^T = K Q^T  (swapped operands: A = K rows, B = Q^T).
    // s[f][nt][r] = S[q = lane15][key = nt*16 + quad*4 + r]
    f32x4 s[2][4];
    __builtin_amdgcn_s_setprio(1);
#pragma unroll
    for (int nt = 0; nt < 4; nt++) {
      const int krow = nt * 16 + lane15;
      bf16x8 kb0 = *(const bf16x8*)(kb + SWZ(krow, quad * 16));
      bf16x8 kb1 = *(const bf16x8*)(kb + SWZ(krow, 64 + quad * 16));
#pragma unroll
      for (int f = 0; f < 2; f++) {
        f32x4 a0 = {};
        a0 = __builtin_amdgcn_mfma_f32_16x16x32_bf16(kb0, qf[f][0], a0, 0, 0, 0);
        a0 = __builtin_amdgcn_mfma_f32_16x16x32_bf16(kb1, qf[f][1], a0, 0, 0, 0);
        s[f][nt] = a0;
      }
    }
    __builtin_amdgcn_s_setprio(0);

    // p = exp2(s)  (scale pre-folded into Q); keys lane-local -> lane-local
    // partial row sum; pack pairs: pa[f][nt] IS the 16x16x16 A-fragment.
    s16x4 pa[2][4];
#pragma unroll
    for (int f = 0; f < 2; f++)
#pragma unroll
      for (int nt = 0; nt < 4; nt++) {
        float p0 = __builtin_amdgcn_exp2f(s[f][nt][0]);
        float p1 = __builtin_amdgcn_exp2f(s[f][nt][1]);
        float p2 = __builtin_amdgcn_exp2f(s[f][nt][2]);
        float p3 = __builtin_amdgcn_exp2f(s[f][nt][3]);
        lsum[f] += (p0 + p1) + (p2 + p3);
        union { uint32_t u[2]; s16x4 v; } cv;
        cv.u[0] = cvt_pk_bf16(p0, p1);
        cv.u[1] = cvt_pk_bf16(p2, p3);
        pa[f][nt] = cv.v;
      }

    // O += P V, K=16 chunks; B-frag: V[16nt+quad*4+j][dt*16+lane15] via b64.
    __builtin_amdgcn_s_setprio(1);
#pragma unroll
    for (int dt = 0; dt < 4; dt++) {
      const int vrow = dt * 16 + lane15;
      s16x4 bv[4];
#pragma unroll
      for (int nt = 0; nt < 4; nt++)
        bv[nt] = *(const s16x4*)(vb + SWZ(vrow, nt * 32 + quad * 8));
#pragma unroll
      for (int f = 0; f < 2; f++) {
        f32x4 t = oacc[f][dt];
#pragma unroll
        for (int nt = 0; nt < 4; nt++)
          t = __builtin_amdgcn_mfma_f32_16x16x16bf16_1k(pa[f][nt], bv[nt], t, 0, 0, 0);
        oacc[f][dt] = t;
      }
    }
    __builtin_amdgcn_s_setprio(0);

    __syncthreads();   // drains vmcnt: nxt staging complete; fences cur
                       // reads before iter+1 overwrites cur.
  }

  // finalize: lsum[f] holds this lane's partial for q = lane15; sum the 4
  // quads (xor16+xor32), then redistribute 1/l to C-layout rows (quad*4+r).
#pragma unroll
  for (int f = 0; f < 2; f++) {
    float lt = lsum[f];
    lt += __shfl_xor(lt, 16);
    lt += __shfl_xor(lt, 32);
    lsum[f] = lt;                    // every lane: total for q = lane15
  }
#pragma unroll
  for (int f = 0; f < 2; f++) {
    float linv[4];
#pragma unroll
    for (int r = 0; r < 4; r++)
      linv[r] = 1.0f / __shfl(lsum[f], quad * 4 + r);
#pragma unroll
    for (int dt = 0; dt < 4; dt++)
#pragma unroll
      for (int r = 0; r < 4; r++) {
        float val = oacc[f][dt][r] * linv[r];
        O[base + (size_t)(q0 + wv * 32 + f * 16 + quad * 4 + r) * D_HALF
          + dt * 16 + lane15] = f2b(val);
      }
  }
}

// ---------------------------------------------------------------------------
// LayerNorm over f32 z rows -> f32 out. One block per row.
// ---------------------------------------------------------------------------
__global__ __launch_bounds__(256)
void ln_kernel(const float* zA, const float* zB,
               const float* gA, const float* bA, const float* gB, const float* bB,
               float* out) {
  const int row = blockIdx.x, br = blockIdx.y;
  const float* z = (br ? zB : zA) + (size_t)row * D_HALF;
  const float* g  = br ? gB : gA;
  const float* be = br ? bB : bA;
  float* o = out + (size_t)br * ((size_t)4096 * D_HALF) + (size_t)row * D_HALF;

  float4 v = ((const float4*)z)[threadIdx.x];
  float s  = v.x + v.y + v.z + v.w;
  float s2 = v.x * v.x + v.y * v.y + v.z * v.z + v.w * v.w;
#pragma unroll
  for (int off = 32; off > 0; off >>= 1) {
    s  += __shfl_down(s, off);
    s2 += __shfl_down(s2, off);
  }
  __shared__ float red[8];
  int w = threadIdx.x >> 6, ln = threadIdx.x & 63;
  if (ln == 0) { red[w] = s; red[4 + w] = s2; }
  __syncthreads();
  if (threadIdx.x == 0) {
    red[0] = red[0] + red[1] + red[2] + red[3];
    red[4] = red[4] + red[5] + red[6] + red[7];
  }
  __syncthreads();
  float mu  = red[0] * (1.0f / 1024.0f);
  float var = red[4] * (1.0f / 1024.0f) - mu * mu;
  float rs  = rsqrtf(fmaxf(var, 0.0f) + 1e-5f);

  int col = threadIdx.x * 4;
  float4 gv = ((const float4*)g)[threadIdx.x];
  float4 bv = ((const float4*)be)[threadIdx.x];
  float4 ov;
  ov.x = (v.x - mu) * rs * gv.x + bv.x;
  ov.y = (v.y - mu) * rs * gv.y + bv.y;
  ov.z = (v.z - mu) * rs * gv.z + bv.z;
  ov.w = (v.w - mu) * rs * gv.w + bv.w;
  *(float4*)&o[col] = ov;
}

// ---------------------------------------------------------------------------
extern "C" void kernel_launch(void* const* d_in, const int* in_sizes, int n_in,
                              void* d_out, int out_size, void* d_ws, size_t ws_size,
                              hipStream_t stream) {
  const float* x_a     = (const float*)d_in[0];
  const float* x_b     = (const float*)d_in[1];
  const float* Wq_a    = (const float*)d_in[2];
  const float* Wq_b    = (const float*)d_in[3];
  const float* Wk_a    = (const float*)d_in[4];
  const float* Wk_b    = (const float*)d_in[5];
  const float* Wv_a    = (const float*)d_in[6];
  const float* Wv_b    = (const float*)d_in[7];
  const float* Wo_a    = (const float*)d_in[8];
  const float* Wo_b    = (const float*)d_in[9];
  const float* gamma_a = (const float*)d_in[10];
  const float* beta_a  = (const float*)d_in[11];
  const float* gamma_b = (const float*)d_in[12];
  const float* beta_b  = (const float*)d_in[13];

  // Workspace map (ws = 64 MB = 32M u16; BUF = 4M u16 = 8 MB):
  //   slots 0-5: q_a,k_a,vt_a,q_b,k_b,vt_b (QKV outputs, read by attn)
  //   ws+24M u16 (48 MB): 8 bf16 weights (Wq/Wk/Wv a,b = 12 MB; Wo a,b = 4 MB)
  //   phase 3: z_a/z_b f32 overwrite slots 0-3 (dead after attn)
  // d_out (32 MB) doubles as scratch:
  //   phase 1: xbf_a/xbf_b (16 MB) read by QKV GEMM
  //   phase 2: o_a/o_b (16 MB) written by attn, read by out-proj
  //   ln writes the final f32 output last.
  const size_t BUF = (size_t)4096 * 1024;
  u16* ws   = (u16*)d_ws;
  u16* q_a  = ws + 0 * BUF; u16* k_a  = ws + 1 * BUF; u16* vt_a = ws + 2 * BUF;
  u16* q_b  = ws + 3 * BUF; u16* k_b  = ws + 4 * BUF; u16* vt_b = ws + 5 * BUF;
  u16* wall = ws + 6 * BUF;                    // 8 x 1M-u16 bf16 weights
  float* z_a = (float*)(ws + 0 * BUF);
  float* z_b = (float*)(ws + 2 * BUF);

  u16* xbf_a = (u16*)d_out;
  u16* xbf_b = xbf_a + 4194304;
  u16* o_a   = (u16*)d_out;                    // reuses xbf region (dead)
  u16* o_b   = o_a + 4194304;

  const int N = 1024, K = 1024;

  CArgAll ca;
  ca.src[0] = x_a;  ca.dst[0] = xbf_a;
  ca.src[1] = x_b;  ca.dst[1] = xbf_b;
  ca.src[2] = Wq_a; ca.src[3] = Wk_a; ca.src[4] = Wv_a;
  ca.src[5] = Wq_b; ca.src[6] = Wk_b; ca.src[7] = Wv_b;
  ca.src[8] = Wo_a; ca.src[9] = Wo_b;
  for (int w = 0; w < 8; w++) ca.dst[2 + w] = wall + (size_t)w * 1048576;
  convall<<<dim3(8192), 256, 0, stream>>>(ca);

  GArgs qkv;
  qkv.g[0] = GArg{xbf_a, wall + 0 * 1048576, q_a,  nullptr, nullptr, 0, EXP2_SCALE};
  qkv.g[1] = GArg{xbf_a, wall + 1 * 1048576, k_a,  nullptr, nullptr, 0, 1.0f};
  qkv.g[2] = GArg{xbf_a, wall + 2 * 1048576, vt_a, nullptr, nullptr, 1, 1.0f};
  qkv.g[3] = GArg{xbf_b, wall + 3 * 1048576, q_b,  nullptr, nullptr, 0, EXP2_SCALE};
  qkv.g[4] = GArg{xbf_b, wall + 4 * 1048576, k_b,  nullptr, nullptr, 0, 1.0f};
  qkv.g[5] = GArg{xbf_b, wall + 5 * 1048576, vt_b, nullptr, nullptr, 1, 1.0f};
  gemm_nt<false><<<dim3(8, 32, 6), 256, 0, stream>>>(qkv, N, K);

  attn_kernel<<<dim3(16, 32, 2), 256, 0, stream>>>(q_a, k_a, vt_a, q_b, k_b, vt_b, o_a, o_b);

  GArgs op;
  op.g[0] = GArg{o_a, wall + 6 * 1048576, nullptr, x_a, z_a, 0, 1.0f};
  op.g[1] = GArg{o_b, wall + 7 * 1048576, nullptr, x_b, z_b, 0, 1.0f};
  op.g[2] = op.g[0]; op.g[3] = op.g[0]; op.g[4] = op.g[0]; op.g[5] = op.g[0];
  gemm_nt<true><<<dim3(8, 32, 2), 256, 0, stream>>>(op, N, K);

  ln_kernel<<<dim3(4096, 2), 256, 0, stream>>>(z_a, z_b, gamma_a, beta_a,
                                               gamma_b, beta_b, (float*)d_out);
}